// Round 9
// baseline (299.172 us; speedup 1.0000x reference)
//
#include <hip/hip_runtime.h>

#define EPSF 1e-8f

constexpr int NI = 48, NC = 48, S = 36, W = 32, D = 1024, NB = 64;
constexpr int CH = 64;            // k-chunk
constexpr int NCH = D / CH;       // 16

typedef _Float16 half8 __attribute__((ext_vector_type(8)));
typedef _Float16 half4 __attribute__((ext_vector_type(4)));
typedef float f32x4 __attribute__((ext_vector_type(4)));

__device__ __forceinline__ f32x4 mfma16(half8 a, half8 b, f32x4 c) {
  return __builtin_amdgcn_mfma_f32_16x16x32_f16(a, b, c, 0, 0, 0);
}

// ---- ws layout (bytes) ----
constexpr size_t OFF_CAPTH = 17408;
constexpr size_t SZ_CAPT   = (size_t)48 * 32 * 1024 * 2;   // 3.15 MB
constexpr size_t OFF_CAPTL = OFF_CAPTH + SZ_CAPT;
constexpr size_t OFF_L     = OFF_CAPTL + SZ_CAPT;
constexpr size_t SZ_L      = (size_t)1536 * 1728 * 4;      // 10.6 MB
constexpr size_t OFF_DQ    = OFF_L + SZ_L;
constexpr size_t SZ_DQ     = (size_t)48 * 36 * 64 * 4;     // 442 KB
constexpr size_t WS_NEED   = OFF_DQ + SZ_DQ;               // ~17.4 MB

// ---------------- standalone prep (fallback path) ----------------
__global__ __launch_bounds__(256) void prep_kernel(
    const float* __restrict__ W1, const float* __restrict__ b1,
    const float* __restrict__ W2,
    const float* __restrict__ convW, const float* __restrict__ convB,
    const float* __restrict__ Wm, const float* __restrict__ bm,
    const float* __restrict__ V, const float* __restrict__ g,
    const float* __restrict__ bo, float* __restrict__ ws) {
  __shared__ float sW1[64][68];
  __shared__ float sW2[64][68];
  __shared__ float wn[256];
  __shared__ float wv[64];
  __shared__ float vscale;
  const int t = threadIdx.x;
  for (int q = t; q < 2048; q += 256) {
    const int m = q >> 10, r = (q >> 4) & 63, c4 = (q & 15) * 4;
    const float* src = (m == 0 ? W1 : W2) + r * 64 + c4;
    float4 v = *reinterpret_cast<const float4*>(src);
    float* dst = (m == 0) ? &sW1[r][c4] : &sW2[r][c4];
    dst[0] = v.x; dst[1] = v.y; dst[2] = v.z; dst[3] = v.w;
  }
  if (t == 0) {
    float s = 0.f;
    for (int h = 0; h < 256; ++h) s += V[h] * V[h];
    vscale = g[0] / sqrtf(s);
  }
  __syncthreads();
  wn[t] = V[t] * vscale;
  __syncthreads();
  if (t < 64) {
    float acc = 0.f;
    for (int h = 0; h < 256; ++h)
      acc += 0.5f * (Wm[t * 512 + 2 * h] + Wm[t * 512 + 2 * h + 1]) * wn[h];
    wv[t] = acc;
  }
  __syncthreads();
  if (t < 64) {
    float acc = 0.f;
    for (int m = 0; m < 64; ++m) {
      float ce = 0.f;
      for (int k = 0; k < 8; ++k) ce += convW[k * 4096 + t * 64 + m];
      acc += 0.125f * ce * wv[m];
    }
    ws[t] = acc;  // cv
  }
  if (t == 0) {
    float bh = 0.f;
    for (int h = 0; h < 256; ++h) bh += 0.5f * (bm[2 * h] + bm[2 * h + 1]) * wn[h];
    float bc = 0.f;
    for (int m = 0; m < 64; ++m) bc += convB[m] * wv[m];
    ws[64] = bh + bc + bo[0];  // bconst
  }
  if (t < 64) {  // u = W2^T b1
    float a = 0.f;
    for (int k = 0; k < 64; ++k) a += b1[k] * sW2[k][t];
    ws[66 + t] = a;
  }
  {  // M = W1^T W2 -> f16 hi/lo at ws+132
    const int i = t >> 2, j0 = (t & 3) * 16;
    float acc[16];
#pragma unroll
    for (int jj = 0; jj < 16; ++jj) acc[jj] = 0.f;
    for (int k = 0; k < 64; ++k) {
      const float w1v = sW1[k][i];
#pragma unroll
      for (int jj = 0; jj < 16; ++jj) acc[jj] += w1v * sW2[k][j0 + jj];
    }
    _Float16* wsM = reinterpret_cast<_Float16*>(ws + 132);
#pragma unroll
    for (int jj = 0; jj < 16; ++jj) {
      const float x = acc[jj];
      const _Float16 h = (_Float16)x;
      wsM[i * 64 + j0 + jj] = h;
      wsM[4096 + i * 64 + j0 + jj] = (_Float16)(x - (float)h);
    }
  }
}

// ---------------- fused pre: gemmL (0..431) + conv_cap (432..1199) + dq (1200..1247) + prep (1248)
__global__ __launch_bounds__(256, 3) void fused_pre(
    const float* __restrict__ captions, const float* __restrict__ images,
    const float* __restrict__ W1, const float* __restrict__ b1,
    const float* __restrict__ W2,
    const float* __restrict__ convW, const float* __restrict__ convB,
    const float* __restrict__ Wm, const float* __restrict__ bm,
    const float* __restrict__ V, const float* __restrict__ g,
    const float* __restrict__ bo,
    float* __restrict__ ws, _Float16* __restrict__ capTH,
    _Float16* __restrict__ capTL, float* __restrict__ dqT,
    float* __restrict__ L) {
  __shared__ union {
    struct { _Float16 sA[2][64][72]; _Float16 sB[2][96][72]; } gm;  // 46080 B
    struct { float sW1[64][68]; float sW2[64][68]; float wn[256]; float wv[64]; float vscale; } p;
    struct { _Float16 tH[64][40]; _Float16 tL[64][40]; } cc;
  } U;
  const int t = threadIdx.x;
  const int bx = blockIdx.x;

  if (bx < 432) {  // ================= gemmL: 64x96 tiles =================
    const int lane = t & 63, wid = t >> 6;
    const int c = lane & 15, g2 = lane >> 4;
    const int bm = bx / 18, bn = bx % 18;  // 24 x 18
    const int m0 = bm * 64, n0 = bn * 96;
    const int wm = wid & 1, wn = wid >> 1;

    f32x4 acc[2][3] = {};
    f32x4 pfA[4], pfB[6];
    auto LD = [&](int ch) {
#pragma unroll
      for (int k = 0; k < 4; ++k) {
        const int u = t + k * 256;
        const int row = u >> 4, c4 = (u & 15) * 4;
        pfA[k] = *reinterpret_cast<const f32x4*>(captions + (size_t)(m0 + row) * 1024 + ch * 64 + c4);
      }
#pragma unroll
      for (int k = 0; k < 6; ++k) {
        const int u = t + k * 256;
        const int row = u >> 4, c4 = (u & 15) * 4;
        pfB[k] = *reinterpret_cast<const f32x4*>(images + (size_t)(n0 + row) * 1024 + ch * 64 + c4);
      }
    };
    auto ST = [&]() {
#pragma unroll
      for (int k = 0; k < 4; ++k) {
        const int u = t + k * 256;
        const int row = u >> 4, c4 = (u & 15) * 4;
        half4 hh, ll;
#pragma unroll
        for (int j = 0; j < 4; ++j) {
          const float x = pfA[k][j];
          hh[j] = (_Float16)x;
          ll[j] = (_Float16)(x - (float)hh[j]);
        }
        *reinterpret_cast<half4*>(&U.gm.sA[0][row][c4]) = hh;
        *reinterpret_cast<half4*>(&U.gm.sA[1][row][c4]) = ll;
      }
#pragma unroll
      for (int k = 0; k < 6; ++k) {
        const int u = t + k * 256;
        const int row = u >> 4, c4 = (u & 15) * 4;
        half4 hh, ll;
#pragma unroll
        for (int j = 0; j < 4; ++j) {
          const float x = pfB[k][j];
          hh[j] = (_Float16)x;
          ll[j] = (_Float16)(x - (float)hh[j]);
        }
        *reinterpret_cast<half4*>(&U.gm.sB[0][row][c4]) = hh;
        *reinterpret_cast<half4*>(&U.gm.sB[1][row][c4]) = ll;
      }
    };
    LD(0);
    for (int ch = 0; ch < NCH; ++ch) {
      __syncthreads();
      ST();
      if (ch < NCH - 1) LD(ch + 1);
      __syncthreads();
#pragma unroll
      for (int ks = 0; ks < 2; ++ks) {
        const int ko = ks * 32 + g2 * 8;
        half8 ah[2], al[2], bh[3], bl[3];
#pragma unroll
        for (int mt = 0; mt < 2; ++mt) {
          ah[mt] = *reinterpret_cast<const half8*>(&U.gm.sA[0][wm * 32 + mt * 16 + c][ko]);
          al[mt] = *reinterpret_cast<const half8*>(&U.gm.sA[1][wm * 32 + mt * 16 + c][ko]);
        }
#pragma unroll
        for (int nt = 0; nt < 3; ++nt) {
          bh[nt] = *reinterpret_cast<const half8*>(&U.gm.sB[0][wn * 48 + nt * 16 + c][ko]);
          bl[nt] = *reinterpret_cast<const half8*>(&U.gm.sB[1][wn * 48 + nt * 16 + c][ko]);
        }
#pragma unroll
        for (int mt = 0; mt < 2; ++mt)
#pragma unroll
          for (int nt = 0; nt < 3; ++nt) {
            acc[mt][nt] = mfma16(ah[mt], bh[nt], acc[mt][nt]);
            acc[mt][nt] = mfma16(ah[mt], bl[nt], acc[mt][nt]);
            acc[mt][nt] = mfma16(al[mt], bh[nt], acc[mt][nt]);
          }
      }
    }
#pragma unroll
    for (int mt = 0; mt < 2; ++mt)
#pragma unroll
      for (int nt = 0; nt < 3; ++nt)
#pragma unroll
        for (int r = 0; r < 4; ++r) {
          const int m = m0 + wm * 32 + mt * 16 + 4 * g2 + r;
          const int n = n0 + wn * 48 + nt * 16 + c;
          float x = acc[mt][nt][r];
          x = x > 0.f ? x : 0.1f * x;
          L[(size_t)m * 1728 + n] = x;
        }
  } else if (bx < 1200) {  // ================= conv_cap =================
    const int b2 = bx - 432;
    const int c = b2 >> 4, chn = b2 & 15, d0 = chn * 64;
    for (int q = t; q < 512; q += 256) {
      const int w = q >> 4, c4 = (q & 15) * 4;
      const size_t gi = ((size_t)c * 32 + w) * 1024 + d0 + c4;
      float4 v = *reinterpret_cast<const float4*>(captions + gi);
      half4 hh, ll;
      hh[0] = (_Float16)v.x; ll[0] = (_Float16)(v.x - (float)hh[0]);
      hh[1] = (_Float16)v.y; ll[1] = (_Float16)(v.y - (float)hh[1]);
      hh[2] = (_Float16)v.z; ll[2] = (_Float16)(v.z - (float)hh[2]);
      hh[3] = (_Float16)v.w; ll[3] = (_Float16)(v.w - (float)hh[3]);
#pragma unroll
      for (int j = 0; j < 4; ++j) { U.cc.tH[c4 + j][w] = hh[j]; U.cc.tL[c4 + j][w] = ll[j]; }
    }
    __syncthreads();
    for (int q = t; q < 512; q += 256) {
      const int hl = q >> 8, dd = (q >> 2) & 63, w8 = (q & 3) * 8;
      half8 v = *reinterpret_cast<const half8*>(hl ? &U.cc.tL[dd][w8] : &U.cc.tH[dd][w8]);
      _Float16* dst = (hl ? capTL : capTH) + ((size_t)c * 1024 + d0 + dd) * 32 + w8;
      *reinterpret_cast<half8*>(dst) = v;
    }
  } else if (bx < 1248) {  // ================= dq table: dqT[i][s][nb] =================
    const int i = bx - 1200;
    for (int u = t; u < 2304; u += 256) {
      const int s = u >> 6, nb = u & 63;
      const float* p = images + ((size_t)i * 36 + s) * 1024 + nb * 16;
      float a = 0.f;
#pragma unroll
      for (int j = 0; j < 16; j += 4) {
        f32x4 v = *reinterpret_cast<const f32x4*>(p + j);
        a += v[0] * v[0] + v[1] * v[1] + v[2] * v[2] + v[3] * v[3];
      }
      dqT[((size_t)i * 36 + s) * 64 + nb] = a;
    }
  } else {  // ================= prep =================
    for (int q = t; q < 2048; q += 256) {
      const int m = q >> 10, r = (q >> 4) & 63, c4 = (q & 15) * 4;
      const float* src = (m == 0 ? W1 : W2) + r * 64 + c4;
      float4 v = *reinterpret_cast<const float4*>(src);
      float* dst = (m == 0) ? &U.p.sW1[r][c4] : &U.p.sW2[r][c4];
      dst[0] = v.x; dst[1] = v.y; dst[2] = v.z; dst[3] = v.w;
    }
    if (t == 0) {
      float s = 0.f;
      for (int h = 0; h < 256; ++h) s += V[h] * V[h];
      U.p.vscale = g[0] / sqrtf(s);
    }
    __syncthreads();
    U.p.wn[t] = V[t] * U.p.vscale;
    __syncthreads();
    if (t < 64) {
      float acc = 0.f;
      for (int h = 0; h < 256; ++h)
        acc += 0.5f * (Wm[t * 512 + 2 * h] + Wm[t * 512 + 2 * h + 1]) * U.p.wn[h];
      U.p.wv[t] = acc;
    }
    __syncthreads();
    if (t < 64) {
      float acc = 0.f;
      for (int m = 0; m < 64; ++m) {
        float ce = 0.f;
        for (int k = 0; k < 8; ++k) ce += convW[k * 4096 + t * 64 + m];
        acc += 0.125f * ce * U.p.wv[m];
      }
      ws[t] = acc;
    }
    if (t == 0) {
      float bh = 0.f;
      for (int h = 0; h < 256; ++h) bh += 0.5f * (bm[2 * h] + bm[2 * h + 1]) * U.p.wn[h];
      float bc = 0.f;
      for (int m = 0; m < 64; ++m) bc += convB[m] * U.p.wv[m];
      ws[64] = bh + bc + bo[0];
    }
    if (t < 64) {
      float a = 0.f;
      for (int k = 0; k < 64; ++k) a += b1[k] * U.p.sW2[k][t];
      ws[66 + t] = a;
    }
    {
      const int i = t >> 2, j0 = (t & 3) * 16;
      float acc[16];
#pragma unroll
      for (int jj = 0; jj < 16; ++jj) acc[jj] = 0.f;
      for (int k = 0; k < 64; ++k) {
        const float w1v = U.p.sW1[k][i];
#pragma unroll
        for (int jj = 0; jj < 16; ++jj) acc[jj] += w1v * U.p.sW2[k][j0 + jj];
      }
      _Float16* wsM = reinterpret_cast<_Float16*>(ws + 132);
#pragma unroll
      for (int jj = 0; jj < 16; ++jj) {
        const float x = acc[jj];
        const _Float16 h = (_Float16)x;
        wsM[i * 64 + j0 + jj] = h;
        wsM[4096 + i * 64 + j0 + jj] = (_Float16)(x - (float)h);
      }
    }
  }
}

// swizzled byte offset within a 36x64-half row-major tile (row stride 128 B)
__device__ __forceinline__ int swz(int row, int nbyte) {
  return row * 128 + (nbyte ^ ((row & 7) << 4));
}

// ---------------- per-(caption, image): atomic-LDS d-reduction, no shuffles ----
__global__ __launch_bounds__(256, 4) void i2t_sim5(
    const float* __restrict__ images,
    const _Float16* __restrict__ capTH, const _Float16* __restrict__ capTL,
    const float* __restrict__ L, const float* __restrict__ dqT,
    const float* __restrict__ delt, const float* __restrict__ ws,
    float* __restrict__ out) {
  __shared__ union {
    float La[32][41];          // 5248 B (phases 1-3)
    float dtdc[36][64][2];     // 18432 B (chunk loop accumulators)
    _Float16 yhl[2][2304];     // 9216 B (tail GEMMs)
  } UA;
  __shared__ union {
    _Float16 attn[2][36][40];  // 5760 B (live through chunk loop)
    float G[36][49];           // 7056 B (tail; cols 0..47 written)
  } UB;
  __shared__ _Float16 simS[2][2304];  // 9216 B (swizzled rows)
  __shared__ float wrcp[32];
  __shared__ float sDelt[64], sCv[64], sU[64];
  __shared__ float sP[36], sScv[36], sRed[36];
  __shared__ float sBconst;

  const int t = threadIdx.x;
  const int lane = t & 63, wid = t >> 6;    // wid 0..3
  const int c = lane & 15, g = lane >> 4;
  const int bid = blockIdx.x;
  const int xcd = bid & 7, l = bid >> 3;    // l < 288
  const int ci = (xcd >> 1) * 12 + (l % 12);
  const int ii = (xcd & 1) * 24 + (l / 12);

  if (t < 64) { sDelt[t] = delt[t]; sCv[t] = ws[t]; sU[t] = ws[66 + t]; }
  if (t == 64) sBconst = ws[64];

  // ---- load L tile (already leaky'd)
#pragma unroll
  for (int k = 0; k < 2; ++k) {
    const int u = t + k * 256;
    if (u < 288) {
      const int w = u / 9, q4 = (u % 9) * 4;
      f32x4 x = *reinterpret_cast<const f32x4*>(
          L + (size_t)(ci * 32 + w) * 1728 + (size_t)ii * 36 + q4);
      *reinterpret_cast<f32x4*>(&UA.La[w][q4]) = x;
    }
  }
  __syncthreads();
  if (t < 32) {  // 1/l2norm over regions per word
    float s = 0.f;
    for (int ss = 0; ss < 36; ++ss) { const float v = UA.La[t][ss]; s += v * v; }
    wrcp[t] = 1.f / (sqrtf(s) + EPSF);
  }
  __syncthreads();
  if (t < 36) {  // softmax over words per region -> attn f16 hi/lo
    float lw[32];
    float m = -1e30f;
#pragma unroll
    for (int w = 0; w < 32; ++w) {
      const float v = 9.f * UA.La[w][t] * wrcp[w];
      lw[w] = v;
      m = fmaxf(m, v);
    }
    float sum = 0.f;
#pragma unroll
    for (int w = 0; w < 32; ++w) { lw[w] = expf(lw[w] - m); sum += lw[w]; }
    const float r = 1.f / sum;
#pragma unroll
    for (int w = 0; w < 32; ++w) {
      const float a = lw[w] * r;
      const _Float16 h = (_Float16)a;
      UB.attn[0][t][w] = h;
      UB.attn[1][t][w] = (_Float16)(a - (float)h);
    }
  }
  __syncthreads();  // La dead; attn live. dtdc init below (per-wave-owned slices).

  // ---- zero own dtdc slice: wave wid owns nb = 4k + wid (no barrier needed)
  for (int k = lane; k < 36 * 16 * 2; k += 64) {
    const int x = k & 1, nbk = (k >> 1) & 15, s = k >> 5;
    UA.dtdc[s][nbk * 4 + wid][x] = 0.f;
  }

  // ---- barrier-free chunk loop: CH=64, 16 chunks; wave wid owns d-rows wid*16..+15
  const size_t abase = ((size_t)ci * 1024 + wid * 16 + c) * 32 + g * 8;
  half8 pAh = *reinterpret_cast<const half8*>(capTH + abase);
  half8 pAl = *reinterpret_cast<const half8*>(capTL + abase);
  const float* pq[3];
  int scl[3];
#pragma unroll
  for (int mt = 0; mt < 3; ++mt) {
    int s = mt * 16 + c; if (s > 35) s = 35;
    scl[mt] = s;
    pq[mt] = images + ((size_t)ii * 36 + s) * 1024 + wid * 16 + 4 * g;
  }
#pragma unroll 1
  for (int ch = 0; ch < 16; ++ch) {
    const half8 Ah = pAh, Al = pAl;
    if (ch < 15) {
      const size_t nx = abase + (size_t)(ch + 1) * 64 * 32;
      pAh = *reinterpret_cast<const half8*>(capTH + nx);
      pAl = *reinterpret_cast<const half8*>(capTL + nx);
    }
    const int nb = ch * 4 + wid;
#pragma unroll
    for (int mt = 0; mt < 3; ++mt) {
      const f32x4 q = *reinterpret_cast<const f32x4*>(pq[mt] + ch * 64);
      const half8 bh = *reinterpret_cast<const half8*>(&UB.attn[0][scl[mt]][g * 8]);
      const half8 bl = *reinterpret_cast<const half8*>(&UB.attn[1][scl[mt]][g * 8]);
      f32x4 a = {0.f, 0.f, 0.f, 0.f};
      a = mfma16(Ah, bh, a);
      a = mfma16(Ah, bl, a);
      a = mfma16(Al, bh, a);
      // lane holds ctx[d = wid*16+4g+r][s = mt*16+c]
      const float dt = a[0] * q[0] + a[1] * q[1] + a[2] * q[2] + a[3] * q[3];
      const float dc = a[0] * a[0] + a[1] * a[1] + a[2] * a[2] + a[3] * a[3];
      const int s = mt * 16 + c;
      if (s < S) {  // fire-and-forget: ds_add_f32, no return, no serial chain
        atomicAdd(&UA.dtdc[s][nb][0], dt);
        atomicAdd(&UA.dtdc[s][nb][1], dc);
      }
    }
  }
  __syncthreads();

  // ---- sim = dt * rsqrt(dq*dc) * delt -> f16 hi/lo swizzled
  {
    char* sb0 = (char*)&simS[0][0];
    char* sb1 = (char*)&simS[1][0];
    const float* pdq = dqT + (size_t)ii * 2304;
    for (int u = t; u < 36 * 64; u += 256) {
      const int s = u >> 6, nb = u & 63;
      const float dt = UA.dtdc[s][nb][0];
      const float dc = UA.dtdc[s][nb][1];
      const float dq = pdq[u];
      const float r = __frsqrt_rn(fmaxf(dq * dc, 1e-16f));
      const float sm = dt * r * sDelt[nb];
      const _Float16 h = (_Float16)sm;
      *reinterpret_cast<_Float16*>(sb0 + swz(s, nb * 2)) = h;
      *reinterpret_cast<_Float16*>(sb1 + swz(s, nb * 2)) = (_Float16)(sm - (float)h);
    }
  }
  __syncthreads();

  // ---- tail
  const _Float16* wsM = reinterpret_cast<const _Float16*>(ws + 132);
  const char* sb0 = (const char*)&simS[0][0];
  const char* sb1 = (const char*)&simS[1][0];
  char* yb0 = (char*)&UA.yhl[0][0];
  char* yb1 = (char*)&UA.yhl[1][0];
  for (int tid = wid; tid < 12; tid += 4) {  // y = sim·M^T
    const int mt = tid >> 2, nt = tid & 3;
    f32x4 a = {0.f, 0.f, 0.f, 0.f};
#pragma unroll
    for (int ks = 0; ks < 2; ++ks) {
      const int ko = ks * 32 + g * 8;
      int ar = mt * 16 + c; if (ar > 35) ar = 35;
      half8 a_h = *reinterpret_cast<const half8*>(sb0 + swz(ar, ko * 2));
      half8 a_l = *reinterpret_cast<const half8*>(sb1 + swz(ar, ko * 2));
      half8 b_h = *reinterpret_cast<const half8*>(wsM + (nt * 16 + c) * 64 + ko);
      half8 b_l = *reinterpret_cast<const half8*>(wsM + 4096 + (nt * 16 + c) * 64 + ko);
      a = mfma16(a_h, b_h, a);
      a = mfma16(a_h, b_l, a);
      a = mfma16(a_l, b_h, a);
    }
#pragma unroll
    for (int r = 0; r < 4; ++r) {
      const int srow = mt * 16 + 4 * g + r;
      const int icol = nt * 16 + c;
      if (srow < S) {
        const float x = a[r];
        const _Float16 h = (_Float16)x;
        *reinterpret_cast<_Float16*>(yb0 + swz(srow, icol * 2)) = h;
        *reinterpret_cast<_Float16*>(yb1 + swz(srow, icol * 2)) = (_Float16)(x - (float)h);
      }
    }
  }
  if (t < 36) {  // p = u·sim ; scv = cv·sim (reads only simS)
    float a = 0.f, b = 0.f;
#pragma unroll
    for (int k8 = 0; k8 < 8; ++k8) {
      half8 v0 = *reinterpret_cast<const half8*>(sb0 + swz(t, k8 * 16));
      half8 v1 = *reinterpret_cast<const half8*>(sb1 + swz(t, k8 * 16));
#pragma unroll
      for (int j = 0; j < 8; ++j) {
        const float sv = (float)v0[j] + (float)v1[j];
        a += sv * sU[k8 * 8 + j];
        b += sv * sCv[k8 * 8 + j];
      }
    }
    sP[t] = a;
    sScv[t] = b;
  }
  __syncthreads();
  for (int tid = wid; tid < 9; tid += 4) {  // G = sim·y^T (UB.G; attn dead)
    const int mt = tid / 3, nt = tid % 3;
    f32x4 a = {0.f, 0.f, 0.f, 0.f};
#pragma unroll
    for (int ks = 0; ks < 2; ++ks) {
      const int ko = ks * 32 + g * 8;
      int ar = mt * 16 + c; if (ar > 35) ar = 35;
      int br = nt * 16 + c; if (br > 35) br = 35;
      half8 a_h = *reinterpret_cast<const half8*>(sb0 + swz(ar, ko * 2));
      half8 a_l = *reinterpret_cast<const half8*>(sb1 + swz(ar, ko * 2));
      half8 b_h = *reinterpret_cast<const half8*>((const char*)yb0 + swz(br, ko * 2));
      half8 b_l = *reinterpret_cast<const half8*>((const char*)yb1 + swz(br, ko * 2));
      a = mfma16(a_h, b_h, a);
      a = mfma16(a_h, b_l, a);
      a = mfma16(a_l, b_h, a);
    }
#pragma unroll
    for (int r = 0; r < 4; ++r) {
      const int srow = mt * 16 + 4 * g + r;
      const int tcol = nt * 16 + c;
      if (srow < S) UB.G[srow][tcol] = a[r];
    }
  }
  __syncthreads();
  if (t < 36) {  // fused row-softmax(G + p) · scv -> tanh
    float lg[36];
    float m = -1e30f;
#pragma unroll
    for (int t2 = 0; t2 < S; ++t2) {
      lg[t2] = UB.G[t][t2] + sP[t2];
      m = fmaxf(m, lg[t2]);
    }
    float se = 0.f, sv = 0.f;
#pragma unroll
    for (int t2 = 0; t2 < S; ++t2) {
      const float e = expf(lg[t2] - m);
      se += e; sv += e * sScv[t2];
    }
    sRed[t] = tanhf(sv / se + sBconst);
  }
  __syncthreads();
  if (t == 0) {
    float a = 0.f;
    for (int s = 0; s < S; ++s) a += sRed[s];
    out[(size_t)ii * NC + ci] = a * (1.f / 36.f);
  }
}

// ---------------- fallback (R2 kernel, used when ws too small) ----------------
constexpr int ST1 = CH + 8;
constexpr int STT = 56;
constexpr int STI = 68;
constexpr int STC = 52;
constexpr int STH = 72;
constexpr int STA = 40;

__global__ __launch_bounds__(256, 2) void i2t_fb(
    const float* __restrict__ images, const float* __restrict__ captions,
    const float* __restrict__ delt, const float* __restrict__ ws,
    float* __restrict__ out) {
  __shared__ union {
    struct { _Float16 cap[2][32][ST1]; _Float16 img[2][48][ST1]; } s1;
    float lpart[4][32][36];
    struct { _Float16 capT[2][64][STT]; float img32[36][STI]; } s2;
    _Float16 M[2][64][STH];
    float G[36][52];
  } rA;
  __shared__ union {
    float La[32][37];
    float ctxT[64][STC];
    _Float16 yhl[2][48][STH];
  } rB;
  __shared__ _Float16 attn_hl[2][48][STA];
  __shared__ _Float16 sim_hl[2][48][STH];
  __shared__ float wrcp[32];
  __shared__ float sDelt[64], sCv[64], sU[64];
  __shared__ float sP[36], sScv[36], sRed[36];
  __shared__ float sBconst;

  const int t = threadIdx.x;
  const int lane = t & 63, wid = t >> 6;
  const int mrow = lane & 15, grp = lane >> 4;
  const int bid = blockIdx.x;
  const int xcd = bid & 7, l = bid >> 3;
  const int ci = (xcd >> 1) * 12 + (l % 12);
  const int ii = (xcd & 1) * 24 + (l / 12);
  const float* cap = captions + ci * (W * D);
  const float* img = images + ii * (S * D);
  const f32x4 zero4 = {0.f, 0.f, 0.f, 0.f};

  if (t < 64) { sDelt[t] = delt[t]; sCv[t] = ws[t]; sU[t] = ws[66 + t]; }
  if (t == 64) sBconst = ws[64];

  f32x4 acc1[2][3];
#pragma unroll
  for (int mt = 0; mt < 2; ++mt)
#pragma unroll
    for (int nt = 0; nt < 3; ++nt) acc1[mt][nt] = zero4;

  for (int ch = 0; ch < NCH; ++ch) {
    const int d0 = ch * CH;
    __syncthreads();
    for (int q = t; q < 1088; q += 256) {
      const int row = q >> 4, c4 = (q & 15) * 4;
      const float* src = (row < 32) ? (cap + row * D + d0 + c4)
                                    : (img + (row - 32) * D + d0 + c4);
      float4 v = *reinterpret_cast<const float4*>(src);
      half4 hh, ll;
      hh[0] = (_Float16)v.x; ll[0] = (_Float16)(v.x - (float)hh[0]);
      hh[1] = (_Float16)v.y; ll[1] = (_Float16)(v.y - (float)hh[1]);
      hh[2] = (_Float16)v.z; ll[2] = (_Float16)(v.z - (float)hh[2]);
      hh[3] = (_Float16)v.w; ll[3] = (_Float16)(v.w - (float)hh[3]);
      _Float16* dh = (row < 32) ? &rA.s1.cap[0][row][c4] : &rA.s1.img[0][row - 32][c4];
      _Float16* dl = (row < 32) ? &rA.s1.cap[1][row][c4] : &rA.s1.img[1][row - 32][c4];
      *reinterpret_cast<half4*>(dh) = hh;
      *reinterpret_cast<half4*>(dl) = ll;
    }
    __syncthreads();
    if ((ch & 3) == wid) {
#pragma unroll
      for (int ks = 0; ks < 2; ++ks) {
        const int ko = ks * 32 + grp * 8;
        half8 ah[2], al[2], bh[3], bl[3];
#pragma unroll
        for (int mt = 0; mt < 2; ++mt) {
          ah[mt] = *reinterpret_cast<const half8*>(&rA.s1.cap[0][mt * 16 + mrow][ko]);
          al[mt] = *reinterpret_cast<const half8*>(&rA.s1.cap[1][mt * 16 + mrow][ko]);
        }
#pragma unroll
        for (int nt = 0; nt < 3; ++nt) {
          bh[nt] = *reinterpret_cast<const half8*>(&rA.s1.img[0][nt * 16 + mrow][ko]);
          bl[nt] = *reinterpret_cast<const half8*>(&rA.s1.img[1][nt * 16 + mrow][ko]);
        }
#pragma unroll
        for (int mt = 0; mt < 2; ++mt)
#pragma unroll
          for (int nt = 0; nt < 3; ++nt) {
            acc1[mt][nt] = mfma16(ah[mt], bh[nt], acc1[mt][nt]);
            acc1[mt][nt] = mfma16(ah[mt], bl[nt], acc1[mt][nt]);
            acc1[mt][nt] = mfma16(al[mt], bh[nt], acc1[mt][nt]);
          }
      }
    }
  }
  __syncthreads();
#pragma unroll
  for (int mt = 0; mt < 2; ++mt)
#pragma unroll
    for (int nt = 0; nt < 3; ++nt)
#pragma unroll
      for (int r = 0; r < 4; ++r) {
        const int w = mt * 16 + grp * 4 + r;
        const int s = nt * 16 + mrow;
        if (s < S) rA.lpart[wid][w][s] = acc1[mt][nt][r];
      }
  __syncthreads();
  {
    const float* lp = &rA.lpart[0][0][0];
    for (int e = t; e < W * S; e += 256) {
      float x = lp[e] + lp[e + 1152] + lp[e + 2304] + lp[e + 3456];
      x = x > 0.f ? x : 0.1f * x;
      rB.La[e / S][e % S] = x;
    }
  }
  __syncthreads();
  if (t < W) {
    float sum = 0.f;
    for (int s = 0; s < S; ++s) { float v = rB.La[t][s]; sum += v * v; }
    wrcp[t] = 1.f / (sqrtf(sum) + EPSF);
  }
  __syncthreads();
  if (t < S) {
    float lw[32];
    float m = -1e30f;
#pragma unroll
    for (int w = 0; w < 32; ++w) {
      float v = 9.f * rB.La[w][t] * wrcp[w];
      lw[w] = v;
      m = fmaxf(m, v);
    }
    float sum = 0.f;
#pragma unroll
    for (int w = 0; w < 32; ++w) { lw[w] = expf(lw[w] - m); sum += lw[w]; }
    const float r = 1.f / sum;
#pragma unroll
    for (int w = 0; w < 32; ++w) {
      float a = lw[w] * r;
      _Float16 h = (_Float16)a;
      attn_hl[0][t][w] = h;
      attn_hl[1][t][w] = (_Float16)(a - (float)h);
    }
  }
  __syncthreads();

  half8 a2h[3], a2l[3];
#pragma unroll
  for (int mt = 0; mt < 3; ++mt) {
    a2h[mt] = *reinterpret_cast<const half8*>(&attn_hl[0][mt * 16 + mrow][grp * 8]);
    a2l[mt] = *reinterpret_cast<const half8*>(&attn_hl[1][mt * 16 + mrow][grp * 8]);
  }
  for (int ch = 0; ch < NCH; ++ch) {
    const int d0 = ch * CH;
    __syncthreads();
    {
      const int dl = t & 63, wb = (t >> 6) * 8;
      half8 hh, ll;
#pragma unroll
      for (int k = 0; k < 8; ++k) {
        float x = cap[(wb + k) * D + d0 + dl];
        hh[k] = (_Float16)x;
        ll[k] = (_Float16)(x - (float)hh[k]);
      }
      *reinterpret_cast<half8*>(&rA.s2.capT[0][dl][wb]) = hh;
      *reinterpret_cast<half8*>(&rA.s2.capT[1][dl][wb]) = ll;
    }
    for (int q = t; q < 576; q += 256) {
      const int sr = q >> 4, c4 = (q & 15) * 4;
      float4 v = *reinterpret_cast<const float4*>(img + sr * D + d0 + c4);
      *reinterpret_cast<float4*>(&rA.s2.img32[sr][c4]) = v;
    }
    __syncthreads();
    {
      const int dloc = wid * 16 + mrow;
      half8 b_h = *reinterpret_cast<const half8*>(&rA.s2.capT[0][dloc][grp * 8]);
      half8 b_l = *reinterpret_cast<const half8*>(&rA.s2.capT[1][dloc][grp * 8]);
#pragma unroll
      for (int mt = 0; mt < 3; ++mt) {
        f32x4 acc = zero4;
        acc = mfma16(a2h[mt], b_h, acc);
        acc = mfma16(a2h[mt], b_l, acc);
        acc = mfma16(a2l[mt], b_h, acc);
        const int s0 = mt * 16 + grp * 4;
        if (s0 < S) *reinterpret_cast<f32x4*>(&rB.ctxT[dloc][s0]) = acc;
      }
    }
    __syncthreads();
    if (t < 144) {
      const int s = t % 36, nbl = t / 36;
      const int n = ch * 4 + nbl;
      float dt = 0.f, dc = 0.f, dq = 0.f;
#pragma unroll
      for (int j4 = 0; j4 < 4; ++j4) {
        f32x4 qv = *reinterpret_cast<const f32x4*>(&rA.s2.img32[s][nbl * 16 + j4 * 4]);
#pragma unroll
        for (int jj = 0; jj < 4; ++jj) {
          float cx = rB.ctxT[nbl * 16 + j4 * 4 + jj][s];
          float q = qv[jj];
          dt += q * cx; dc += cx * cx; dq += q * q;
        }
      }
      float sim = dt / fmaxf(sqrtf(dq) * sqrtf(dc), EPSF) * sDelt[n];
      _Float16 h = (_Float16)sim;
      sim_hl[0][s][n] = h;
      sim_hl[1][s][n] = (_Float16)(sim - (float)h);
    }
  }
  __syncthreads();

  for (int q = t; q < 1024; q += 256) {
    const int hl = q >> 9, row = (q >> 3) & 63, c8 = (q & 7) * 8;
    const _Float16* wsM = reinterpret_cast<const _Float16*>(ws + 132);
    *reinterpret_cast<half8*>(&rA.M[hl][row][c8]) =
        *reinterpret_cast<const half8*>(wsM + hl * 4096 + row * 64 + c8);
  }
  __syncthreads();
  for (int tid = wid; tid < 12; tid += 4) {
    const int mt = tid >> 2, nt = tid & 3;
    f32x4 acc = zero4;
#pragma unroll
    for (int ks = 0; ks < 2; ++ks) {
      const int ko = ks * 32 + grp * 8;
      half8 a_h = *reinterpret_cast<const half8*>(&sim_hl[0][mt * 16 + mrow][ko]);
      half8 a_l = *reinterpret_cast<const half8*>(&sim_hl[1][mt * 16 + mrow][ko]);
      half8 b_h = *reinterpret_cast<const half8*>(&rA.M[0][nt * 16 + mrow][ko]);
      half8 b_l = *reinterpret_cast<const half8*>(&rA.M[1][nt * 16 + mrow][ko]);
      acc = mfma16(a_h, b_h, acc);
      acc = mfma16(a_h, b_l, acc);
      acc = mfma16(a_l, b_h, acc);
    }
#pragma unroll
    for (int r = 0; r < 4; ++r) {
      const int srow = mt * 16 + grp * 4 + r;
      const int icol = nt * 16 + mrow;
      float x = acc[r];
      _Float16 h = (_Float16)x;
      rB.yhl[0][srow][icol] = h;
      rB.yhl[1][srow][icol] = (_Float16)(x - (float)h);
    }
  }
  __syncthreads();
  for (int tid = wid; tid < 9; tid += 4) {
    const int mt = tid / 3, nt = tid % 3;
    f32x4 acc = zero4;
#pragma unroll
    for (int ks = 0; ks < 2; ++ks) {
      const int ko = ks * 32 + grp * 8;
      half8 a_h = *reinterpret_cast<const half8*>(&sim_hl[0][mt * 16 + mrow][ko]);
      half8 a_l = *reinterpret_cast<const half8*>(&sim_hl[1][mt * 16 + mrow][ko]);
      half8 b_h = *reinterpret_cast<const half8*>(&rB.yhl[0][nt * 16 + mrow][ko]);
      half8 b_l = *reinterpret_cast<const half8*>(&rB.yhl[1][nt * 16 + mrow][ko]);
      acc = mfma16(a_h, b_h, acc);
      acc = mfma16(a_h, b_l, acc);
      acc = mfma16(a_l, b_h, acc);
    }
#pragma unroll
    for (int r = 0; r < 4; ++r) {
      const int srow = mt * 16 + grp * 4 + r;
      const int tcol = nt * 16 + mrow;
      if (srow < S) rA.G[srow][tcol] = acc[r];
    }
  }
  __syncthreads();
  if (t < S) {
    float a = 0.f;
#pragma unroll
    for (int n = 0; n < 64; ++n)
      a += ((float)sim_hl[0][t][n] + (float)sim_hl[1][t][n]) * sU[n];
    sP[t] = a;
  } else if (t >= 64 && t < 64 + S) {
    const int r = t - 64;
    float a = 0.f;
#pragma unroll
    for (int n = 0; n < 64; ++n)
      a += ((float)sim_hl[0][r][n] + (float)sim_hl[1][r][n]) * sCv[n];
    sScv[r] = a;
  }
  __syncthreads();
  if (t < S) {
    float lg[36];
    float m = -1e30f;
#pragma unroll
    for (int t2 = 0; t2 < S; ++t2) {
      lg[t2] = rA.G[t][t2] + sP[t2];
      m = fmaxf(m, lg[t2]);
    }
    float se = 0.f, sv = 0.f;
#pragma unroll
    for (int t2 = 0; t2 < S; ++t2) {
      float e = expf(lg[t2] - m);
      se += e; sv += e * sScv[t2];
    }
    sRed[t] = tanhf(sv / se + sBconst);
  }
  __syncthreads();
  if (t == 0) {
    float a = 0.f;
    for (int s = 0; s < S; ++s) a += sRed[s];
    out[ii * NC + ci] = a * (1.f / 36.f);
  }
}

extern "C" void kernel_launch(void* const* d_in, const int* in_sizes, int n_in,
                              void* d_out, int out_size, void* d_ws, size_t ws_size,
                              hipStream_t stream) {
  const float* images   = (const float*)d_in[0];
  const float* captions = (const float*)d_in[1];
  // d_in[2] = cap_lens (unused: reference uniformizes to full length)
  const float* delt  = (const float*)d_in[3];
  const float* W1    = (const float*)d_in[4];
  const float* b1    = (const float*)d_in[5];
  const float* W2    = (const float*)d_in[6];
  // d_in[7] = b2: cancels inside the row-softmax, unused
  const float* convW = (const float*)d_in[8];
  const float* convB = (const float*)d_in[9];
  const float* Wm    = (const float*)d_in[10];
  const float* bm    = (const float*)d_in[11];
  const float* V     = (const float*)d_in[12];
  const float* g     = (const float*)d_in[13];
  const float* bo    = (const float*)d_in[14];
  float* ws  = (float*)d_ws;
  float* out = (float*)d_out;

  if (ws_size >= WS_NEED) {
    char* base = (char*)d_ws;
    _Float16* capTH = (_Float16*)(base + OFF_CAPTH);
    _Float16* capTL = (_Float16*)(base + OFF_CAPTL);
    float*    Lbuf  = (float*)(base + OFF_L);
    float*    dqT   = (float*)(base + OFF_DQ);
    fused_pre<<<dim3(1249), 256, 0, stream>>>(captions, images, W1, b1, W2,
                                              convW, convB, Wm, bm, V, g, bo,
                                              ws, capTH, capTL, dqT, Lbuf);
    i2t_sim5<<<dim3(2304), 256, 0, stream>>>(images, capTH, capTL, Lbuf, dqT,
                                             delt, ws, out);
  } else {
    prep_kernel<<<1, 256, 0, stream>>>(W1, b1, W2, convW, convB, Wm, bm, V, g, bo, ws);
    i2t_fb<<<dim3(NI * NC), 256, 0, stream>>>(images, captions, delt, ws, out);
  }
}

// Round 10
// 147.931 us; speedup vs baseline: 2.0224x; 2.0224x over previous
//
#include <hip/hip_runtime.h>

#define EPSF 1e-8f

constexpr int NI = 48, NC = 48, S = 36, W = 32, D = 1024, NB = 64;
constexpr int CH = 64;            // k-chunk
constexpr int NCH = D / CH;       // 16

typedef _Float16 half8 __attribute__((ext_vector_type(8)));
typedef _Float16 half4 __attribute__((ext_vector_type(4)));
typedef float f32x4 __attribute__((ext_vector_type(4)));

__device__ __forceinline__ f32x4 mfma16(half8 a, half8 b, f32x4 c) {
  return __builtin_amdgcn_mfma_f32_16x16x32_f16(a, b, c, 0, 0, 0);
}

// ---- ws layout (bytes) ----
constexpr size_t OFF_CAPTH = 17408;
constexpr size_t SZ_CAPT   = (size_t)48 * 32 * 1024 * 2;   // 3.15 MB
constexpr size_t OFF_CAPTL = OFF_CAPTH + SZ_CAPT;
constexpr size_t OFF_L     = OFF_CAPTL + SZ_CAPT;
constexpr size_t SZ_L      = (size_t)1536 * 1728 * 4;      // 10.6 MB
constexpr size_t OFF_DQ    = OFF_L + SZ_L;
constexpr size_t SZ_DQ     = (size_t)48 * 64 * 36 * 4;     // 442 KB
constexpr size_t WS_NEED   = OFF_DQ + SZ_DQ;               // ~17.4 MB

// ---------------- standalone prep (fallback path) ----------------
__global__ __launch_bounds__(256) void prep_kernel(
    const float* __restrict__ W1, const float* __restrict__ b1,
    const float* __restrict__ W2,
    const float* __restrict__ convW, const float* __restrict__ convB,
    const float* __restrict__ Wm, const float* __restrict__ bm,
    const float* __restrict__ V, const float* __restrict__ g,
    const float* __restrict__ bo, float* __restrict__ ws) {
  __shared__ float sW1[64][68];
  __shared__ float sW2[64][68];
  __shared__ float wn[256];
  __shared__ float wv[64];
  __shared__ float vscale;
  const int t = threadIdx.x;
  for (int q = t; q < 2048; q += 256) {
    const int m = q >> 10, r = (q >> 4) & 63, c4 = (q & 15) * 4;
    const float* src = (m == 0 ? W1 : W2) + r * 64 + c4;
    float4 v = *reinterpret_cast<const float4*>(src);
    float* dst = (m == 0) ? &sW1[r][c4] : &sW2[r][c4];
    dst[0] = v.x; dst[1] = v.y; dst[2] = v.z; dst[3] = v.w;
  }
  if (t == 0) {
    float s = 0.f;
    for (int h = 0; h < 256; ++h) s += V[h] * V[h];
    vscale = g[0] / sqrtf(s);
  }
  __syncthreads();
  wn[t] = V[t] * vscale;
  __syncthreads();
  if (t < 64) {
    float acc = 0.f;
    for (int h = 0; h < 256; ++h)
      acc += 0.5f * (Wm[t * 512 + 2 * h] + Wm[t * 512 + 2 * h + 1]) * wn[h];
    wv[t] = acc;
  }
  __syncthreads();
  if (t < 64) {
    float acc = 0.f;
    for (int m = 0; m < 64; ++m) {
      float ce = 0.f;
      for (int k = 0; k < 8; ++k) ce += convW[k * 4096 + t * 64 + m];
      acc += 0.125f * ce * wv[m];
    }
    ws[t] = acc;  // cv
  }
  if (t == 0) {
    float bh = 0.f;
    for (int h = 0; h < 256; ++h) bh += 0.5f * (bm[2 * h] + bm[2 * h + 1]) * wn[h];
    float bc = 0.f;
    for (int m = 0; m < 64; ++m) bc += convB[m] * wv[m];
    ws[64] = bh + bc + bo[0];  // bconst
  }
  if (t < 64) {  // u = W2^T b1
    float a = 0.f;
    for (int k = 0; k < 64; ++k) a += b1[k] * sW2[k][t];
    ws[66 + t] = a;
  }
  {  // M = W1^T W2 -> f16 hi/lo at ws+132
    const int i = t >> 2, j0 = (t & 3) * 16;
    float acc[16];
#pragma unroll
    for (int jj = 0; jj < 16; ++jj) acc[jj] = 0.f;
    for (int k = 0; k < 64; ++k) {
      const float w1v = sW1[k][i];
#pragma unroll
      for (int jj = 0; jj < 16; ++jj) acc[jj] += w1v * sW2[k][j0 + jj];
    }
    _Float16* wsM = reinterpret_cast<_Float16*>(ws + 132);
#pragma unroll
    for (int jj = 0; jj < 16; ++jj) {
      const float x = acc[jj];
      const _Float16 h = (_Float16)x;
      wsM[i * 64 + j0 + jj] = h;
      wsM[4096 + i * 64 + j0 + jj] = (_Float16)(x - (float)h);
    }
  }
}

// ---------------- fused pre: gemmL (0..431) + conv_cap (432..1199) + dq (1200..1247) + prep (1248)
__global__ __launch_bounds__(256, 3) void fused_pre(
    const float* __restrict__ captions, const float* __restrict__ images,
    const float* __restrict__ W1, const float* __restrict__ b1,
    const float* __restrict__ W2,
    const float* __restrict__ convW, const float* __restrict__ convB,
    const float* __restrict__ Wm, const float* __restrict__ bm,
    const float* __restrict__ V, const float* __restrict__ g,
    const float* __restrict__ bo,
    float* __restrict__ ws, _Float16* __restrict__ capTH,
    _Float16* __restrict__ capTL, float* __restrict__ dqT,
    float* __restrict__ L) {
  __shared__ union {
    struct { _Float16 sA[2][64][72]; _Float16 sB[2][96][72]; } gm;  // 46080 B
    struct { float sW1[64][68]; float sW2[64][68]; float wn[256]; float wv[64]; float vscale; } p;
    struct { _Float16 tH[64][40]; _Float16 tL[64][40]; } cc;
  } U;
  const int t = threadIdx.x;
  const int bx = blockIdx.x;

  if (bx < 432) {  // ================= gemmL: 64x96 tiles =================
    const int lane = t & 63, wid = t >> 6;
    const int c = lane & 15, g2 = lane >> 4;
    const int bm = bx / 18, bn = bx % 18;  // 24 x 18
    const int m0 = bm * 64, n0 = bn * 96;
    const int wm = wid & 1, wn = wid >> 1;

    f32x4 acc[2][3] = {};
    f32x4 pfA[4], pfB[6];
    auto LD = [&](int ch) {
#pragma unroll
      for (int k = 0; k < 4; ++k) {
        const int u = t + k * 256;
        const int row = u >> 4, c4 = (u & 15) * 4;
        pfA[k] = *reinterpret_cast<const f32x4*>(captions + (size_t)(m0 + row) * 1024 + ch * 64 + c4);
      }
#pragma unroll
      for (int k = 0; k < 6; ++k) {
        const int u = t + k * 256;
        const int row = u >> 4, c4 = (u & 15) * 4;
        pfB[k] = *reinterpret_cast<const f32x4*>(images + (size_t)(n0 + row) * 1024 + ch * 64 + c4);
      }
    };
    auto ST = [&]() {
#pragma unroll
      for (int k = 0; k < 4; ++k) {
        const int u = t + k * 256;
        const int row = u >> 4, c4 = (u & 15) * 4;
        half4 hh, ll;
#pragma unroll
        for (int j = 0; j < 4; ++j) {
          const float x = pfA[k][j];
          hh[j] = (_Float16)x;
          ll[j] = (_Float16)(x - (float)hh[j]);
        }
        *reinterpret_cast<half4*>(&U.gm.sA[0][row][c4]) = hh;
        *reinterpret_cast<half4*>(&U.gm.sA[1][row][c4]) = ll;
      }
#pragma unroll
      for (int k = 0; k < 6; ++k) {
        const int u = t + k * 256;
        const int row = u >> 4, c4 = (u & 15) * 4;
        half4 hh, ll;
#pragma unroll
        for (int j = 0; j < 4; ++j) {
          const float x = pfB[k][j];
          hh[j] = (_Float16)x;
          ll[j] = (_Float16)(x - (float)hh[j]);
        }
        *reinterpret_cast<half4*>(&U.gm.sB[0][row][c4]) = hh;
        *reinterpret_cast<half4*>(&U.gm.sB[1][row][c4]) = ll;
      }
    };
    LD(0);
    for (int ch = 0; ch < NCH; ++ch) {
      __syncthreads();
      ST();
      if (ch < NCH - 1) LD(ch + 1);
      __syncthreads();
#pragma unroll
      for (int ks = 0; ks < 2; ++ks) {
        const int ko = ks * 32 + g2 * 8;
        half8 ah[2], al[2], bh[3], bl[3];
#pragma unroll
        for (int mt = 0; mt < 2; ++mt) {
          ah[mt] = *reinterpret_cast<const half8*>(&U.gm.sA[0][wm * 32 + mt * 16 + c][ko]);
          al[mt] = *reinterpret_cast<const half8*>(&U.gm.sA[1][wm * 32 + mt * 16 + c][ko]);
        }
#pragma unroll
        for (int nt = 0; nt < 3; ++nt) {
          bh[nt] = *reinterpret_cast<const half8*>(&U.gm.sB[0][wn * 48 + nt * 16 + c][ko]);
          bl[nt] = *reinterpret_cast<const half8*>(&U.gm.sB[1][wn * 48 + nt * 16 + c][ko]);
        }
#pragma unroll
        for (int mt = 0; mt < 2; ++mt)
#pragma unroll
          for (int nt = 0; nt < 3; ++nt) {
            acc[mt][nt] = mfma16(ah[mt], bh[nt], acc[mt][nt]);
            acc[mt][nt] = mfma16(ah[mt], bl[nt], acc[mt][nt]);
            acc[mt][nt] = mfma16(al[mt], bh[nt], acc[mt][nt]);
          }
      }
    }
#pragma unroll
    for (int mt = 0; mt < 2; ++mt)
#pragma unroll
      for (int nt = 0; nt < 3; ++nt)
#pragma unroll
        for (int r = 0; r < 4; ++r) {
          const int m = m0 + wm * 32 + mt * 16 + 4 * g2 + r;
          const int n = n0 + wn * 48 + nt * 16 + c;
          float x = acc[mt][nt][r];
          x = x > 0.f ? x : 0.1f * x;
          L[(size_t)m * 1728 + n] = x;
        }
  } else if (bx < 1200) {  // ================= conv_cap =================
    const int b2 = bx - 432;
    const int c = b2 >> 4, chn = b2 & 15, d0 = chn * 64;
    for (int q = t; q < 512; q += 256) {
      const int w = q >> 4, c4 = (q & 15) * 4;
      const size_t gi = ((size_t)c * 32 + w) * 1024 + d0 + c4;
      float4 v = *reinterpret_cast<const float4*>(captions + gi);
      half4 hh, ll;
      hh[0] = (_Float16)v.x; ll[0] = (_Float16)(v.x - (float)hh[0]);
      hh[1] = (_Float16)v.y; ll[1] = (_Float16)(v.y - (float)hh[1]);
      hh[2] = (_Float16)v.z; ll[2] = (_Float16)(v.z - (float)hh[2]);
      hh[3] = (_Float16)v.w; ll[3] = (_Float16)(v.w - (float)hh[3]);
#pragma unroll
      for (int j = 0; j < 4; ++j) { U.cc.tH[c4 + j][w] = hh[j]; U.cc.tL[c4 + j][w] = ll[j]; }
    }
    __syncthreads();
    for (int q = t; q < 512; q += 256) {
      const int hl = q >> 8, dd = (q >> 2) & 63, w8 = (q & 3) * 8;
      half8 v = *reinterpret_cast<const half8*>(hl ? &U.cc.tL[dd][w8] : &U.cc.tH[dd][w8]);
      _Float16* dst = (hl ? capTL : capTH) + ((size_t)c * 1024 + d0 + dd) * 32 + w8;
      *reinterpret_cast<half8*>(dst) = v;
    }
  } else if (bx < 1248) {  // ================= dq table: dqT[i][nb][s] =================
    const int i = bx - 1200;
    for (int u = t; u < 2304; u += 256) {
      const int s = u >> 6, nb = u & 63;
      const float* p = images + ((size_t)i * 36 + s) * 1024 + nb * 16;
      float a = 0.f;
#pragma unroll
      for (int j = 0; j < 16; j += 4) {
        f32x4 v = *reinterpret_cast<const f32x4*>(p + j);
        a += v[0] * v[0] + v[1] * v[1] + v[2] * v[2] + v[3] * v[3];
      }
      dqT[((size_t)i * 64 + nb) * 36 + s] = a;
    }
  } else {  // ================= prep =================
    for (int q = t; q < 2048; q += 256) {
      const int m = q >> 10, r = (q >> 4) & 63, c4 = (q & 15) * 4;
      const float* src = (m == 0 ? W1 : W2) + r * 64 + c4;
      float4 v = *reinterpret_cast<const float4*>(src);
      float* dst = (m == 0) ? &U.p.sW1[r][c4] : &U.p.sW2[r][c4];
      dst[0] = v.x; dst[1] = v.y; dst[2] = v.z; dst[3] = v.w;
    }
    if (t == 0) {
      float s = 0.f;
      for (int h = 0; h < 256; ++h) s += V[h] * V[h];
      U.p.vscale = g[0] / sqrtf(s);
    }
    __syncthreads();
    U.p.wn[t] = V[t] * U.p.vscale;
    __syncthreads();
    if (t < 64) {
      float acc = 0.f;
      for (int h = 0; h < 256; ++h)
        acc += 0.5f * (Wm[t * 512 + 2 * h] + Wm[t * 512 + 2 * h + 1]) * U.p.wn[h];
      U.p.wv[t] = acc;
    }
    __syncthreads();
    if (t < 64) {
      float acc = 0.f;
      for (int m = 0; m < 64; ++m) {
        float ce = 0.f;
        for (int k = 0; k < 8; ++k) ce += convW[k * 4096 + t * 64 + m];
        acc += 0.125f * ce * U.p.wv[m];
      }
      ws[t] = acc;
    }
    if (t == 0) {
      float bh = 0.f;
      for (int h = 0; h < 256; ++h) bh += 0.5f * (bm[2 * h] + bm[2 * h + 1]) * U.p.wn[h];
      float bc = 0.f;
      for (int m = 0; m < 64; ++m) bc += convB[m] * U.p.wv[m];
      ws[64] = bh + bc + bo[0];
    }
    if (t < 64) {
      float a = 0.f;
      for (int k = 0; k < 64; ++k) a += b1[k] * U.p.sW2[k][t];
      ws[66 + t] = a;
    }
    {
      const int i = t >> 2, j0 = (t & 3) * 16;
      float acc[16];
#pragma unroll
      for (int jj = 0; jj < 16; ++jj) acc[jj] = 0.f;
      for (int k = 0; k < 64; ++k) {
        const float w1v = U.p.sW1[k][i];
#pragma unroll
        for (int jj = 0; jj < 16; ++jj) acc[jj] += w1v * U.p.sW2[k][j0 + jj];
      }
      _Float16* wsM = reinterpret_cast<_Float16*>(ws + 132);
#pragma unroll
      for (int jj = 0; jj < 16; ++jj) {
        const float x = acc[jj];
        const _Float16 h = (_Float16)x;
        wsM[i * 64 + j0 + jj] = h;
        wsM[4096 + i * 64 + j0 + jj] = (_Float16)(x - (float)h);
      }
    }
  }
}

// swizzled byte offset within a 36x64-half row-major tile (row stride 128 B)
__device__ __forceinline__ int swz(int row, int nbyte) {
  return row * 128 + (nbyte ^ ((row & 7) << 4));
}

// ---------------- per-(caption, image) kernel: 256 thr, small LDS, high TLP ----
__global__ __launch_bounds__(256, 5) void i2t_sim4(
    const float* __restrict__ images,
    const _Float16* __restrict__ capTH, const _Float16* __restrict__ capTL,
    const float* __restrict__ L, const float* __restrict__ dqT,
    const float* __restrict__ delt, const float* __restrict__ ws,
    float* __restrict__ out) {
  __shared__ union {
    float La[32][41];          // 5248 B (phases 1-3)
    _Float16 yhl[2][2304];     // 9216 B (tail)
  } UA;
  __shared__ union {
    _Float16 attn[2][36][40];  // 5760 B (live through chunk loop)
    float G[36][49];           // 7056 B (tail; cols 0..47 written by 3x16 tiles)
  } UB;
  __shared__ _Float16 simS[2][2304];  // 9216 B (swizzled rows)
  __shared__ float wrcp[32];
  __shared__ float sDelt[64], sCv[64], sU[64];
  __shared__ float sP[36], sScv[36], sRed[36];
  __shared__ float sBconst;

  const int t = threadIdx.x;
  const int lane = t & 63, wid = t >> 6;    // wid 0..3
  const int c = lane & 15, g = lane >> 4;
  const int bid = blockIdx.x;
  const int xcd = bid & 7, l = bid >> 3;    // l < 288
  const int ci = (xcd >> 1) * 12 + (l % 12);
  const int ii = (xcd & 1) * 24 + (l / 12);

  if (t < 64) { sDelt[t] = delt[t]; sCv[t] = ws[t]; sU[t] = ws[66 + t]; }
  if (t == 64) sBconst = ws[64];

  // ---- load L tile (already leaky'd)
#pragma unroll
  for (int k = 0; k < 2; ++k) {
    const int u = t + k * 256;
    if (u < 288) {
      const int w = u / 9, q4 = (u % 9) * 4;
      f32x4 x = *reinterpret_cast<const f32x4*>(
          L + (size_t)(ci * 32 + w) * 1728 + (size_t)ii * 36 + q4);
      *reinterpret_cast<f32x4*>(&UA.La[w][q4]) = x;
    }
  }
  __syncthreads();
  if (t < 32) {  // 1/l2norm over regions per word
    float s = 0.f;
    for (int ss = 0; ss < 36; ++ss) { const float v = UA.La[t][ss]; s += v * v; }
    wrcp[t] = 1.f / (sqrtf(s) + EPSF);
  }
  __syncthreads();
  if (t < 36) {  // softmax over words per region -> attn f16 hi/lo
    float lw[32];
    float m = -1e30f;
#pragma unroll
    for (int w = 0; w < 32; ++w) {
      const float v = 9.f * UA.La[w][t] * wrcp[w];
      lw[w] = v;
      m = fmaxf(m, v);
    }
    float sum = 0.f;
#pragma unroll
    for (int w = 0; w < 32; ++w) { lw[w] = expf(lw[w] - m); sum += lw[w]; }
    const float r = 1.f / sum;
#pragma unroll
    for (int w = 0; w < 32; ++w) {
      const float a = lw[w] * r;
      const _Float16 h = (_Float16)a;
      UB.attn[0][t][w] = h;
      UB.attn[1][t][w] = (_Float16)(a - (float)h);
    }
  }
  __syncthreads();

  // ---- barrier-free chunk loop: CH=64, 16 chunks; wave wid owns d-rows wid*16..+15
  const size_t abase = ((size_t)ci * 1024 + wid * 16 + c) * 32 + g * 8;
  half8 pAh = *reinterpret_cast<const half8*>(capTH + abase);
  half8 pAl = *reinterpret_cast<const half8*>(capTL + abase);
  const float* pq[3];
  int scl[3];
  const float* pdqB = dqT + (size_t)ii * 64 * 36;
#pragma unroll
  for (int mt = 0; mt < 3; ++mt) {
    int s = mt * 16 + c; if (s > 35) s = 35;
    scl[mt] = s;
    pq[mt] = images + ((size_t)ii * 36 + s) * 1024 + wid * 16 + 4 * g;
  }
#pragma unroll 1
  for (int ch = 0; ch < 16; ++ch) {
    const half8 Ah = pAh, Al = pAl;
    if (ch < 15) {
      const size_t nx = abase + (size_t)(ch + 1) * 64 * 32;
      pAh = *reinterpret_cast<const half8*>(capTH + nx);
      pAl = *reinterpret_cast<const half8*>(capTL + nx);
    }
    const int nb = ch * 4 + wid;
    // phase a: issue the chunk's global loads up front
    f32x4 qv[3];
    float dqv[3];
#pragma unroll
    for (int mt = 0; mt < 3; ++mt) {
      qv[mt] = *reinterpret_cast<const f32x4*>(pq[mt] + ch * 64);
      dqv[mt] = pdqB[(size_t)nb * 36 + scl[mt]];
    }
    // phase b: 3 independent MFMA+dot chains
    float dts[3], dcs[3];
#pragma unroll
    for (int mt = 0; mt < 3; ++mt) {
      const half8 bh = *reinterpret_cast<const half8*>(&UB.attn[0][scl[mt]][g * 8]);
      const half8 bl = *reinterpret_cast<const half8*>(&UB.attn[1][scl[mt]][g * 8]);
      f32x4 a = {0.f, 0.f, 0.f, 0.f};
      a = mfma16(Ah, bh, a);
      a = mfma16(Ah, bl, a);
      a = mfma16(Al, bh, a);
      const f32x4 q = qv[mt];
      dts[mt] = a[0] * q[0] + a[1] * q[1] + a[2] * q[2] + a[3] * q[3];
      dcs[mt] = a[0] * a[0] + a[1] * a[1] + a[2] * a[2] + a[3] * a[3];
    }
    // phase c: batched shuffle reductions + stores
#pragma unroll
    for (int mt = 0; mt < 3; ++mt) {
      float dt = dts[mt], dc = dcs[mt];
      dt += __shfl_xor(dt, 16); dc += __shfl_xor(dc, 16);
      dt += __shfl_xor(dt, 32); dc += __shfl_xor(dc, 32);
      const int s = mt * 16 + c;
      if (g == 0 && s < S) {
        const float r = __frsqrt_rn(fmaxf(dqv[mt] * dc, 1e-16f));
        const float sm = dt * r * sDelt[nb];
        const _Float16 h = (_Float16)sm;
        char* sb0 = (char*)&simS[0][0];
        char* sb1 = (char*)&simS[1][0];
        *reinterpret_cast<_Float16*>(sb0 + swz(s, nb * 2)) = h;
        *reinterpret_cast<_Float16*>(sb1 + swz(s, nb * 2)) = (_Float16)(sm - (float)h);
      }
    }
  }
  __syncthreads();

  // ---- tail
  const _Float16* wsM = reinterpret_cast<const _Float16*>(ws + 132);
  const char* sb0 = (const char*)&simS[0][0];
  const char* sb1 = (const char*)&simS[1][0];
  char* yb0 = (char*)&UA.yhl[0][0];
  char* yb1 = (char*)&UA.yhl[1][0];
  for (int tid = wid; tid < 12; tid += 4) {  // y = sim·M^T
    const int mt = tid >> 2, nt = tid & 3;
    f32x4 a = {0.f, 0.f, 0.f, 0.f};
#pragma unroll
    for (int ks = 0; ks < 2; ++ks) {
      const int ko = ks * 32 + g * 8;
      int ar = mt * 16 + c; if (ar > 35) ar = 35;
      half8 a_h = *reinterpret_cast<const half8*>(sb0 + swz(ar, ko * 2));
      half8 a_l = *reinterpret_cast<const half8*>(sb1 + swz(ar, ko * 2));
      half8 b_h = *reinterpret_cast<const half8*>(wsM + (nt * 16 + c) * 64 + ko);
      half8 b_l = *reinterpret_cast<const half8*>(wsM + 4096 + (nt * 16 + c) * 64 + ko);
      a = mfma16(a_h, b_h, a);
      a = mfma16(a_h, b_l, a);
      a = mfma16(a_l, b_h, a);
    }
#pragma unroll
    for (int r = 0; r < 4; ++r) {
      const int srow = mt * 16 + 4 * g + r;
      const int icol = nt * 16 + c;
      if (srow < S) {
        const float x = a[r];
        const _Float16 h = (_Float16)x;
        *reinterpret_cast<_Float16*>(yb0 + swz(srow, icol * 2)) = h;
        *reinterpret_cast<_Float16*>(yb1 + swz(srow, icol * 2)) = (_Float16)(x - (float)h);
      }
    }
  }
  if (t < 36) {  // p = u·sim ; scv = cv·sim (reads only simS)
    float a = 0.f, b = 0.f;
#pragma unroll
    for (int k8 = 0; k8 < 8; ++k8) {
      half8 v0 = *reinterpret_cast<const half8*>(sb0 + swz(t, k8 * 16));
      half8 v1 = *reinterpret_cast<const half8*>(sb1 + swz(t, k8 * 16));
#pragma unroll
      for (int j = 0; j < 8; ++j) {
        const float sv = (float)v0[j] + (float)v1[j];
        a += sv * sU[k8 * 8 + j];
        b += sv * sCv[k8 * 8 + j];
      }
    }
    sP[t] = a;
    sScv[t] = b;
  }
  __syncthreads();
  for (int tid = wid; tid < 9; tid += 4) {  // G = sim·y^T (UB.G; attn dead)
    const int mt = tid / 3, nt = tid % 3;
    f32x4 a = {0.f, 0.f, 0.f, 0.f};
#pragma unroll
    for (int ks = 0; ks < 2; ++ks) {
      const int ko = ks * 32 + g * 8;
      int ar = mt * 16 + c; if (ar > 35) ar = 35;
      int br = nt * 16 + c; if (br > 35) br = 35;
      half8 a_h = *reinterpret_cast<const half8*>(sb0 + swz(ar, ko * 2));
      half8 a_l = *reinterpret_cast<const half8*>(sb1 + swz(ar, ko * 2));
      half8 b_h = *reinterpret_cast<const half8*>((const char*)yb0 + swz(br, ko * 2));
      half8 b_l = *reinterpret_cast<const half8*>((const char*)yb1 + swz(br, ko * 2));
      a = mfma16(a_h, b_h, a);
      a = mfma16(a_h, b_l, a);
      a = mfma16(a_l, b_h, a);
    }
#pragma unroll
    for (int r = 0; r < 4; ++r) {
      const int srow = mt * 16 + 4 * g + r;
      const int tcol = nt * 16 + c;
      if (srow < S) UB.G[srow][tcol] = a[r];
    }
  }
  __syncthreads();
  if (t < 36) {  // fused row-softmax(G + p) · scv -> tanh
    float lg[36];
    float m = -1e30f;
#pragma unroll
    for (int t2 = 0; t2 < S; ++t2) {
      lg[t2] = UB.G[t][t2] + sP[t2];
      m = fmaxf(m, lg[t2]);
    }
    float se = 0.f, sv = 0.f;
#pragma unroll
    for (int t2 = 0; t2 < S; ++t2) {
      const float e = expf(lg[t2] - m);
      se += e; sv += e * sScv[t2];
    }
    sRed[t] = tanhf(sv / se + sBconst);
  }
  __syncthreads();
  if (t == 0) {
    float a = 0.f;
    for (int s = 0; s < S; ++s) a += sRed[s];
    out[(size_t)ii * NC + ci] = a * (1.f / 36.f);
  }
}

// ---------------- fallback (R2 kernel, used when ws too small) ----------------
constexpr int ST1 = CH + 8;
constexpr int STT = 56;
constexpr int STI = 68;
constexpr int STC = 52;
constexpr int STH = 72;
constexpr int STA = 40;

__global__ __launch_bounds__(256, 2) void i2t_fb(
    const float* __restrict__ images, const float* __restrict__ captions,
    const float* __restrict__ delt, const float* __restrict__ ws,
    float* __restrict__ out) {
  __shared__ union {
    struct { _Float16 cap[2][32][ST1]; _Float16 img[2][48][ST1]; } s1;
    float lpart[4][32][36];
    struct { _Float16 capT[2][64][STT]; float img32[36][STI]; } s2;
    _Float16 M[2][64][STH];
    float G[36][52];
  } rA;
  __shared__ union {
    float La[32][37];
    float ctxT[64][STC];
    _Float16 yhl[2][48][STH];
  } rB;
  __shared__ _Float16 attn_hl[2][48][STA];
  __shared__ _Float16 sim_hl[2][48][STH];
  __shared__ float wrcp[32];
  __shared__ float sDelt[64], sCv[64], sU[64];
  __shared__ float sP[36], sScv[36], sRed[36];
  __shared__ float sBconst;

  const int t = threadIdx.x;
  const int lane = t & 63, wid = t >> 6;
  const int mrow = lane & 15, grp = lane >> 4;
  const int bid = blockIdx.x;
  const int xcd = bid & 7, l = bid >> 3;
  const int ci = (xcd >> 1) * 12 + (l % 12);
  const int ii = (xcd & 1) * 24 + (l / 12);
  const float* cap = captions + ci * (W * D);
  const float* img = images + ii * (S * D);
  const f32x4 zero4 = {0.f, 0.f, 0.f, 0.f};

  if (t < 64) { sDelt[t] = delt[t]; sCv[t] = ws[t]; sU[t] = ws[66 + t]; }
  if (t == 64) sBconst = ws[64];

  f32x4 acc1[2][3];
#pragma unroll
  for (int mt = 0; mt < 2; ++mt)
#pragma unroll
    for (int nt = 0; nt < 3; ++nt) acc1[mt][nt] = zero4;

  for (int ch = 0; ch < NCH; ++ch) {
    const int d0 = ch * CH;
    __syncthreads();
    for (int q = t; q < 1088; q += 256) {
      const int row = q >> 4, c4 = (q & 15) * 4;
      const float* src = (row < 32) ? (cap + row * D + d0 + c4)
                                    : (img + (row - 32) * D + d0 + c4);
      float4 v = *reinterpret_cast<const float4*>(src);
      half4 hh, ll;
      hh[0] = (_Float16)v.x; ll[0] = (_Float16)(v.x - (float)hh[0]);
      hh[1] = (_Float16)v.y; ll[1] = (_Float16)(v.y - (float)hh[1]);
      hh[2] = (_Float16)v.z; ll[2] = (_Float16)(v.z - (float)hh[2]);
      hh[3] = (_Float16)v.w; ll[3] = (_Float16)(v.w - (float)hh[3]);
      _Float16* dh = (row < 32) ? &rA.s1.cap[0][row][c4] : &rA.s1.img[0][row - 32][c4];
      _Float16* dl = (row < 32) ? &rA.s1.cap[1][row][c4] : &rA.s1.img[1][row - 32][c4];
      *reinterpret_cast<half4*>(dh) = hh;
      *reinterpret_cast<half4*>(dl) = ll;
    }
    __syncthreads();
    if ((ch & 3) == wid) {
#pragma unroll
      for (int ks = 0; ks < 2; ++ks) {
        const int ko = ks * 32 + grp * 8;
        half8 ah[2], al[2], bh[3], bl[3];
#pragma unroll
        for (int mt = 0; mt < 2; ++mt) {
          ah[mt] = *reinterpret_cast<const half8*>(&rA.s1.cap[0][mt * 16 + mrow][ko]);
          al[mt] = *reinterpret_cast<const half8*>(&rA.s1.cap[1][mt * 16 + mrow][ko]);
        }
#pragma unroll
        for (int nt = 0; nt < 3; ++nt) {
          bh[nt] = *reinterpret_cast<const half8*>(&rA.s1.img[0][nt * 16 + mrow][ko]);
          bl[nt] = *reinterpret_cast<const half8*>(&rA.s1.img[1][nt * 16 + mrow][ko]);
        }
#pragma unroll
        for (int mt = 0; mt < 2; ++mt)
#pragma unroll
          for (int nt = 0; nt < 3; ++nt) {
            acc1[mt][nt] = mfma16(ah[mt], bh[nt], acc1[mt][nt]);
            acc1[mt][nt] = mfma16(ah[mt], bl[nt], acc1[mt][nt]);
            acc1[mt][nt] = mfma16(al[mt], bh[nt], acc1[mt][nt]);
          }
      }
    }
  }
  __syncthreads();
#pragma unroll
  for (int mt = 0; mt < 2; ++mt)
#pragma unroll
    for (int nt = 0; nt < 3; ++nt)
#pragma unroll
      for (int r = 0; r < 4; ++r) {
        const int w = mt * 16 + grp * 4 + r;
        const int s = nt * 16 + mrow;
        if (s < S) rA.lpart[wid][w][s] = acc1[mt][nt][r];
      }
  __syncthreads();
  {
    const float* lp = &rA.lpart[0][0][0];
    for (int e = t; e < W * S; e += 256) {
      float x = lp[e] + lp[e + 1152] + lp[e + 2304] + lp[e + 3456];
      x = x > 0.f ? x : 0.1f * x;
      rB.La[e / S][e % S] = x;
    }
  }
  __syncthreads();
  if (t < W) {
    float sum = 0.f;
    for (int s = 0; s < S; ++s) { float v = rB.La[t][s]; sum += v * v; }
    wrcp[t] = 1.f / (sqrtf(sum) + EPSF);
  }
  __syncthreads();
  if (t < S) {
    float lw[32];
    float m = -1e30f;
#pragma unroll
    for (int w = 0; w < 32; ++w) {
      float v = 9.f * rB.La[w][t] * wrcp[w];
      lw[w] = v;
      m = fmaxf(m, v);
    }
    float sum = 0.f;
#pragma unroll
    for (int w = 0; w < 32; ++w) { lw[w] = expf(lw[w] - m); sum += lw[w]; }
    const float r = 1.f / sum;
#pragma unroll
    for (int w = 0; w < 32; ++w) {
      float a = lw[w] * r;
      _Float16 h = (_Float16)a;
      attn_hl[0][t][w] = h;
      attn_hl[1][t][w] = (_Float16)(a - (float)h);
    }
  }
  __syncthreads();

  half8 a2h[3], a2l[3];
#pragma unroll
  for (int mt = 0; mt < 3; ++mt) {
    a2h[mt] = *reinterpret_cast<const half8*>(&attn_hl[0][mt * 16 + mrow][grp * 8]);
    a2l[mt] = *reinterpret_cast<const half8*>(&attn_hl[1][mt * 16 + mrow][grp * 8]);
  }
  for (int ch = 0; ch < NCH; ++ch) {
    const int d0 = ch * CH;
    __syncthreads();
    {
      const int dl = t & 63, wb = (t >> 6) * 8;
      half8 hh, ll;
#pragma unroll
      for (int k = 0; k < 8; ++k) {
        float x = cap[(wb + k) * D + d0 + dl];
        hh[k] = (_Float16)x;
        ll[k] = (_Float16)(x - (float)hh[k]);
      }
      *reinterpret_cast<half8*>(&rA.s2.capT[0][dl][wb]) = hh;
      *reinterpret_cast<half8*>(&rA.s2.capT[1][dl][wb]) = ll;
    }
    for (int q = t; q < 576; q += 256) {
      const int sr = q >> 4, c4 = (q & 15) * 4;
      float4 v = *reinterpret_cast<const float4*>(img + sr * D + d0 + c4);
      *reinterpret_cast<float4*>(&rA.s2.img32[sr][c4]) = v;
    }
    __syncthreads();
    {
      const int dloc = wid * 16 + mrow;
      half8 b_h = *reinterpret_cast<const half8*>(&rA.s2.capT[0][dloc][grp * 8]);
      half8 b_l = *reinterpret_cast<const half8*>(&rA.s2.capT[1][dloc][grp * 8]);
#pragma unroll
      for (int mt = 0; mt < 3; ++mt) {
        f32x4 acc = zero4;
        acc = mfma16(a2h[mt], b_h, acc);
        acc = mfma16(a2h[mt], b_l, acc);
        acc = mfma16(a2l[mt], b_h, acc);
        const int s0 = mt * 16 + grp * 4;
        if (s0 < S) *reinterpret_cast<f32x4*>(&rB.ctxT[dloc][s0]) = acc;
      }
    }
    __syncthreads();
    if (t < 144) {
      const int s = t % 36, nbl = t / 36;
      const int n = ch * 4 + nbl;
      float dt = 0.f, dc = 0.f, dq = 0.f;
#pragma unroll
      for (int j4 = 0; j4 < 4; ++j4) {
        f32x4 qv = *reinterpret_cast<const f32x4*>(&rA.s2.img32[s][nbl * 16 + j4 * 4]);
#pragma unroll
        for (int jj = 0; jj < 4; ++jj) {
          float cx = rB.ctxT[nbl * 16 + j4 * 4 + jj][s];
          float q = qv[jj];
          dt += q * cx; dc += cx * cx; dq += q * q;
        }
      }
      float sim = dt / fmaxf(sqrtf(dq) * sqrtf(dc), EPSF) * sDelt[n];
      _Float16 h = (_Float16)sim;
      sim_hl[0][s][n] = h;
      sim_hl[1][s][n] = (_Float16)(sim - (float)h);
    }
  }
  __syncthreads();

  for (int q = t; q < 1024; q += 256) {
    const int hl = q >> 9, row = (q >> 3) & 63, c8 = (q & 7) * 8;
    const _Float16* wsM = reinterpret_cast<const _Float16*>(ws + 132);
    *reinterpret_cast<half8*>(&rA.M[hl][row][c8]) =
        *reinterpret_cast<const half8*>(wsM + hl * 4096 + row * 64 + c8);
  }
  __syncthreads();
  for (int tid = wid; tid < 12; tid += 4) {
    const int mt = tid >> 2, nt = tid & 3;
    f32x4 acc = zero4;
#pragma unroll
    for (int ks = 0; ks < 2; ++ks) {
      const int ko = ks * 32 + grp * 8;
      half8 a_h = *reinterpret_cast<const half8*>(&sim_hl[0][mt * 16 + mrow][ko]);
      half8 a_l = *reinterpret_cast<const half8*>(&sim_hl[1][mt * 16 + mrow][ko]);
      half8 b_h = *reinterpret_cast<const half8*>(&rA.M[0][nt * 16 + mrow][ko]);
      half8 b_l = *reinterpret_cast<const half8*>(&rA.M[1][nt * 16 + mrow][ko]);
      acc = mfma16(a_h, b_h, acc);
      acc = mfma16(a_h, b_l, acc);
      acc = mfma16(a_l, b_h, acc);
    }
#pragma unroll
    for (int r = 0; r < 4; ++r) {
      const int srow = mt * 16 + grp * 4 + r;
      const int icol = nt * 16 + mrow;
      float x = acc[r];
      _Float16 h = (_Float16)x;
      rB.yhl[0][srow][icol] = h;
      rB.yhl[1][srow][icol] = (_Float16)(x - (float)h);
    }
  }
  __syncthreads();
  for (int tid = wid; tid < 9; tid += 4) {
    const int mt = tid / 3, nt = tid % 3;
    f32x4 acc = zero4;
#pragma unroll
    for (int ks = 0; ks < 2; ++ks) {
      const int ko = ks * 32 + grp * 8;
      half8 a_h = *reinterpret_cast<const half8*>(&sim_hl[0][mt * 16 + mrow][ko]);
      half8 a_l = *reinterpret_cast<const half8*>(&sim_hl[1][mt * 16 + mrow][ko]);
      half8 b_h = *reinterpret_cast<const half8*>(&rB.yhl[0][nt * 16 + mrow][ko]);
      half8 b_l = *reinterpret_cast<const half8*>(&rB.yhl[1][nt * 16 + mrow][ko]);
      acc = mfma16(a_h, b_h, acc);
      acc = mfma16(a_h, b_l, acc);
      acc = mfma16(a_l, b_h, acc);
    }
#pragma unroll
    for (int r = 0; r < 4; ++r) {
      const int srow = mt * 16 + grp * 4 + r;
      const int tcol = nt * 16 + mrow;
      if (srow < S) rA.G[srow][tcol] = acc[r];
    }
  }
  __syncthreads();
  if (t < S) {
    float a = 0.f;
#pragma unroll
    for (int n = 0; n < 64; ++n)
      a += ((float)sim_hl[0][t][n] + (float)sim_hl[1][t][n]) * sU[n];
    sP[t] = a;
  } else if (t >= 64 && t < 64 + S) {
    const int r = t - 64;
    float a = 0.f;
#pragma unroll
    for (int n = 0; n < 64; ++n)
      a += ((float)sim_hl[0][r][n] + (float)sim_hl[1][r][n]) * sCv[n];
    sScv[r] = a;
  }
  __syncthreads();
  if (t < S) {
    float lg[36];
    float m = -1e30f;
#pragma unroll
    for (int t2 = 0; t2 < S; ++t2) {
      lg[t2] = rA.G[t][t2] + sP[t2];
      m = fmaxf(m, lg[t2]);
    }
    float se = 0.f, sv = 0.f;
#pragma unroll
    for (int t2 = 0; t2 < S; ++t2) {
      float e = expf(lg[t2] - m);
      se += e; sv += e * sScv[t2];
    }
    sRed[t] = tanhf(sv / se + sBconst);
  }
  __syncthreads();
  if (t == 0) {
    float a = 0.f;
    for (int s = 0; s < S; ++s) a += sRed[s];
    out[ii * NC + ci] = a * (1.f / 36.f);
  }
}

extern "C" void kernel_launch(void* const* d_in, const int* in_sizes, int n_in,
                              void* d_out, int out_size, void* d_ws, size_t ws_size,
                              hipStream_t stream) {
  const float* images   = (const float*)d_in[0];
  const float* captions = (const float*)d_in[1];
  // d_in[2] = cap_lens (unused: reference uniformizes to full length)
  const float* delt  = (const float*)d_in[3];
  const float* W1    = (const float*)d_in[4];
  const float* b1    = (const float*)d_in[5];
  const float* W2    = (const float*)d_in[6];
  // d_in[7] = b2: cancels inside the row-softmax, unused
  const float* convW = (const float*)d_in[8];
  const float* convB = (const float*)d_in[9];
  const float* Wm    = (const float*)d_in[10];
  const float* bm    = (const float*)d_in[11];
  const float* V     = (const float*)d_in[12];
  const float* g     = (const float*)d_in[13];
  const float* bo    = (const float*)d_in[14];
  float* ws  = (float*)d_ws;
  float* out = (float*)d_out;

  if (ws_size >= WS_NEED) {
    char* base = (char*)d_ws;
    _Float16* capTH = (_Float16*)(base + OFF_CAPTH);
    _Float16* capTL = (_Float16*)(base + OFF_CAPTL);
    float*    Lbuf  = (float*)(base + OFF_L);
    float*    dqT   = (float*)(base + OFF_DQ);
    fused_pre<<<dim3(1249), 256, 0, stream>>>(captions, images, W1, b1, W2,
                                              convW, convB, Wm, bm, V, g, bo,
                                              ws, capTH, capTL, dqT, Lbuf);
    i2t_sim4<<<dim3(2304), 256, 0, stream>>>(images, capTH, capTL, Lbuf, dqT,
                                             delt, ws, out);
  } else {
    prep_kernel<<<1, 256, 0, stream>>>(W1, b1, W2, convW, convB, Wm, bm, V, g, bo, ws);
    i2t_fb<<<dim3(NI * NC), 256, 0, stream>>>(images, captions, delt, ws, out);
  }
}

// Round 11
// 145.645 us; speedup vs baseline: 2.0541x; 1.0157x over previous
//
#include <hip/hip_runtime.h>

#define EPSF 1e-8f

constexpr int NI = 48, NC = 48, S = 36, W = 32, D = 1024, NB = 64;
constexpr int CH = 64;            // k-chunk
constexpr int NCH = D / CH;       // 16

typedef _Float16 half8 __attribute__((ext_vector_type(8)));
typedef _Float16 half4 __attribute__((ext_vector_type(4)));
typedef float f32x4 __attribute__((ext_vector_type(4)));

__device__ __forceinline__ f32x4 mfma16(half8 a, half8 b, f32x4 c) {
  return __builtin_amdgcn_mfma_f32_16x16x32_f16(a, b, c, 0, 0, 0);
}

// ---- ws layout (bytes) ----
constexpr size_t OFF_CAPTH = 17408;
constexpr size_t SZ_CAPT   = (size_t)48 * 32 * 1024 * 2;   // 3.15 MB
constexpr size_t OFF_CAPTL = OFF_CAPTH + SZ_CAPT;
constexpr size_t OFF_L     = OFF_CAPTL + SZ_CAPT;
constexpr size_t SZ_L      = (size_t)1536 * 1728 * 4;      // 10.6 MB
constexpr size_t OFF_DQ    = OFF_L + SZ_L;
constexpr size_t SZ_DQ     = (size_t)48 * 64 * 36 * 4;     // 442 KB
constexpr size_t WS_NEED   = OFF_DQ + SZ_DQ;               // ~17.4 MB

// ---------------- standalone prep (fallback path) ----------------
__global__ __launch_bounds__(256) void prep_kernel(
    const float* __restrict__ W1, const float* __restrict__ b1,
    const float* __restrict__ W2,
    const float* __restrict__ convW, const float* __restrict__ convB,
    const float* __restrict__ Wm, const float* __restrict__ bm,
    const float* __restrict__ V, const float* __restrict__ g,
    const float* __restrict__ bo, float* __restrict__ ws) {
  __shared__ float sW1[64][68];
  __shared__ float sW2[64][68];
  __shared__ float wn[256];
  __shared__ float wv[64];
  __shared__ float vscale;
  const int t = threadIdx.x;
  for (int q = t; q < 2048; q += 256) {
    const int m = q >> 10, r = (q >> 4) & 63, c4 = (q & 15) * 4;
    const float* src = (m == 0 ? W1 : W2) + r * 64 + c4;
    float4 v = *reinterpret_cast<const float4*>(src);
    float* dst = (m == 0) ? &sW1[r][c4] : &sW2[r][c4];
    dst[0] = v.x; dst[1] = v.y; dst[2] = v.z; dst[3] = v.w;
  }
  if (t == 0) {
    float s = 0.f;
    for (int h = 0; h < 256; ++h) s += V[h] * V[h];
    vscale = g[0] / sqrtf(s);
  }
  __syncthreads();
  wn[t] = V[t] * vscale;
  __syncthreads();
  if (t < 64) {
    float acc = 0.f;
    for (int h = 0; h < 256; ++h)
      acc += 0.5f * (Wm[t * 512 + 2 * h] + Wm[t * 512 + 2 * h + 1]) * wn[h];
    wv[t] = acc;
  }
  __syncthreads();
  if (t < 64) {
    float acc = 0.f;
    for (int m = 0; m < 64; ++m) {
      float ce = 0.f;
      for (int k = 0; k < 8; ++k) ce += convW[k * 4096 + t * 64 + m];
      acc += 0.125f * ce * wv[m];
    }
    ws[t] = acc;  // cv
  }
  if (t == 0) {
    float bh = 0.f;
    for (int h = 0; h < 256; ++h) bh += 0.5f * (bm[2 * h] + bm[2 * h + 1]) * wn[h];
    float bc = 0.f;
    for (int m = 0; m < 64; ++m) bc += convB[m] * wv[m];
    ws[64] = bh + bc + bo[0];  // bconst
  }
  if (t < 64) {  // u = W2^T b1
    float a = 0.f;
    for (int k = 0; k < 64; ++k) a += b1[k] * sW2[k][t];
    ws[66 + t] = a;
  }
  {  // M = W1^T W2 -> f16 hi/lo at ws+132
    const int i = t >> 2, j0 = (t & 3) * 16;
    float acc[16];
#pragma unroll
    for (int jj = 0; jj < 16; ++jj) acc[jj] = 0.f;
    for (int k = 0; k < 64; ++k) {
      const float w1v = sW1[k][i];
#pragma unroll
      for (int jj = 0; jj < 16; ++jj) acc[jj] += w1v * sW2[k][j0 + jj];
    }
    _Float16* wsM = reinterpret_cast<_Float16*>(ws + 132);
#pragma unroll
    for (int jj = 0; jj < 16; ++jj) {
      const float x = acc[jj];
      const _Float16 h = (_Float16)x;
      wsM[i * 64 + j0 + jj] = h;
      wsM[4096 + i * 64 + j0 + jj] = (_Float16)(x - (float)h);
    }
  }
}

// ---------------- fused pre: gemmL (0..431) + conv_cap (432..1199) + dq (1200..1247) + prep (1248)
__global__ __launch_bounds__(256, 3) void fused_pre(
    const float* __restrict__ captions, const float* __restrict__ images,
    const float* __restrict__ W1, const float* __restrict__ b1,
    const float* __restrict__ W2,
    const float* __restrict__ convW, const float* __restrict__ convB,
    const float* __restrict__ Wm, const float* __restrict__ bm,
    const float* __restrict__ V, const float* __restrict__ g,
    const float* __restrict__ bo,
    float* __restrict__ ws, _Float16* __restrict__ capTH,
    _Float16* __restrict__ capTL, float* __restrict__ dqT,
    float* __restrict__ L) {
  __shared__ union {
    struct { _Float16 sA[2][64][72]; _Float16 sB[2][96][72]; } gm;  // 46080 B
    struct { float sW1[64][68]; float sW2[64][68]; float wn[256]; float wv[64]; float vscale; } p;
    struct { _Float16 tH[64][40]; _Float16 tL[64][40]; } cc;
  } U;
  const int t = threadIdx.x;
  const int bx = blockIdx.x;

  if (bx < 432) {  // ================= gemmL: 64x96 tiles =================
    const int lane = t & 63, wid = t >> 6;
    const int c = lane & 15, g2 = lane >> 4;
    const int bm = bx / 18, bn = bx % 18;  // 24 x 18
    const int m0 = bm * 64, n0 = bn * 96;
    const int wm = wid & 1, wn = wid >> 1;

    f32x4 acc[2][3] = {};
    f32x4 pfA[4], pfB[6];
    auto LD = [&](int ch) {
#pragma unroll
      for (int k = 0; k < 4; ++k) {
        const int u = t + k * 256;
        const int row = u >> 4, c4 = (u & 15) * 4;
        pfA[k] = *reinterpret_cast<const f32x4*>(captions + (size_t)(m0 + row) * 1024 + ch * 64 + c4);
      }
#pragma unroll
      for (int k = 0; k < 6; ++k) {
        const int u = t + k * 256;
        const int row = u >> 4, c4 = (u & 15) * 4;
        pfB[k] = *reinterpret_cast<const f32x4*>(images + (size_t)(n0 + row) * 1024 + ch * 64 + c4);
      }
    };
    auto ST = [&]() {
#pragma unroll
      for (int k = 0; k < 4; ++k) {
        const int u = t + k * 256;
        const int row = u >> 4, c4 = (u & 15) * 4;
        half4 hh, ll;
#pragma unroll
        for (int j = 0; j < 4; ++j) {
          const float x = pfA[k][j];
          hh[j] = (_Float16)x;
          ll[j] = (_Float16)(x - (float)hh[j]);
        }
        *reinterpret_cast<half4*>(&U.gm.sA[0][row][c4]) = hh;
        *reinterpret_cast<half4*>(&U.gm.sA[1][row][c4]) = ll;
      }
#pragma unroll
      for (int k = 0; k < 6; ++k) {
        const int u = t + k * 256;
        const int row = u >> 4, c4 = (u & 15) * 4;
        half4 hh, ll;
#pragma unroll
        for (int j = 0; j < 4; ++j) {
          const float x = pfB[k][j];
          hh[j] = (_Float16)x;
          ll[j] = (_Float16)(x - (float)hh[j]);
        }
        *reinterpret_cast<half4*>(&U.gm.sB[0][row][c4]) = hh;
        *reinterpret_cast<half4*>(&U.gm.sB[1][row][c4]) = ll;
      }
    };
    LD(0);
    for (int ch = 0; ch < NCH; ++ch) {
      __syncthreads();
      ST();
      if (ch < NCH - 1) LD(ch + 1);
      __syncthreads();
#pragma unroll
      for (int ks = 0; ks < 2; ++ks) {
        const int ko = ks * 32 + g2 * 8;
        half8 ah[2], al[2], bh[3], bl[3];
#pragma unroll
        for (int mt = 0; mt < 2; ++mt) {
          ah[mt] = *reinterpret_cast<const half8*>(&U.gm.sA[0][wm * 32 + mt * 16 + c][ko]);
          al[mt] = *reinterpret_cast<const half8*>(&U.gm.sA[1][wm * 32 + mt * 16 + c][ko]);
        }
#pragma unroll
        for (int nt = 0; nt < 3; ++nt) {
          bh[nt] = *reinterpret_cast<const half8*>(&U.gm.sB[0][wn * 48 + nt * 16 + c][ko]);
          bl[nt] = *reinterpret_cast<const half8*>(&U.gm.sB[1][wn * 48 + nt * 16 + c][ko]);
        }
#pragma unroll
        for (int mt = 0; mt < 2; ++mt)
#pragma unroll
          for (int nt = 0; nt < 3; ++nt) {
            acc[mt][nt] = mfma16(ah[mt], bh[nt], acc[mt][nt]);
            acc[mt][nt] = mfma16(ah[mt], bl[nt], acc[mt][nt]);
            acc[mt][nt] = mfma16(al[mt], bh[nt], acc[mt][nt]);
          }
      }
    }
#pragma unroll
    for (int mt = 0; mt < 2; ++mt)
#pragma unroll
      for (int nt = 0; nt < 3; ++nt)
#pragma unroll
        for (int r = 0; r < 4; ++r) {
          const int m = m0 + wm * 32 + mt * 16 + 4 * g2 + r;
          const int n = n0 + wn * 48 + nt * 16 + c;
          float x = acc[mt][nt][r];
          x = x > 0.f ? x : 0.1f * x;
          L[(size_t)m * 1728 + n] = x;
        }
  } else if (bx < 1200) {  // ================= conv_cap =================
    const int b2 = bx - 432;
    const int c = b2 >> 4, chn = b2 & 15, d0 = chn * 64;
    for (int q = t; q < 512; q += 256) {
      const int w = q >> 4, c4 = (q & 15) * 4;
      const size_t gi = ((size_t)c * 32 + w) * 1024 + d0 + c4;
      float4 v = *reinterpret_cast<const float4*>(captions + gi);
      half4 hh, ll;
      hh[0] = (_Float16)v.x; ll[0] = (_Float16)(v.x - (float)hh[0]);
      hh[1] = (_Float16)v.y; ll[1] = (_Float16)(v.y - (float)hh[1]);
      hh[2] = (_Float16)v.z; ll[2] = (_Float16)(v.z - (float)hh[2]);
      hh[3] = (_Float16)v.w; ll[3] = (_Float16)(v.w - (float)hh[3]);
#pragma unroll
      for (int j = 0; j < 4; ++j) { U.cc.tH[c4 + j][w] = hh[j]; U.cc.tL[c4 + j][w] = ll[j]; }
    }
    __syncthreads();
    for (int q = t; q < 512; q += 256) {
      const int hl = q >> 8, dd = (q >> 2) & 63, w8 = (q & 3) * 8;
      half8 v = *reinterpret_cast<const half8*>(hl ? &U.cc.tL[dd][w8] : &U.cc.tH[dd][w8]);
      _Float16* dst = (hl ? capTL : capTH) + ((size_t)c * 1024 + d0 + dd) * 32 + w8;
      *reinterpret_cast<half8*>(dst) = v;
    }
  } else if (bx < 1248) {  // ================= dq table: dqT[i][nb][s] =================
    const int i = bx - 1200;
    for (int u = t; u < 2304; u += 256) {
      const int s = u >> 6, nb = u & 63;
      const float* p = images + ((size_t)i * 36 + s) * 1024 + nb * 16;
      float a = 0.f;
#pragma unroll
      for (int j = 0; j < 16; j += 4) {
        f32x4 v = *reinterpret_cast<const f32x4*>(p + j);
        a += v[0] * v[0] + v[1] * v[1] + v[2] * v[2] + v[3] * v[3];
      }
      dqT[((size_t)i * 64 + nb) * 36 + s] = a;
    }
  } else {  // ================= prep =================
    for (int q = t; q < 2048; q += 256) {
      const int m = q >> 10, r = (q >> 4) & 63, c4 = (q & 15) * 4;
      const float* src = (m == 0 ? W1 : W2) + r * 64 + c4;
      float4 v = *reinterpret_cast<const float4*>(src);
      float* dst = (m == 0) ? &U.p.sW1[r][c4] : &U.p.sW2[r][c4];
      dst[0] = v.x; dst[1] = v.y; dst[2] = v.z; dst[3] = v.w;
    }
    if (t == 0) {
      float s = 0.f;
      for (int h = 0; h < 256; ++h) s += V[h] * V[h];
      U.p.vscale = g[0] / sqrtf(s);
    }
    __syncthreads();
    U.p.wn[t] = V[t] * U.p.vscale;
    __syncthreads();
    if (t < 64) {
      float acc = 0.f;
      for (int h = 0; h < 256; ++h)
        acc += 0.5f * (Wm[t * 512 + 2 * h] + Wm[t * 512 + 2 * h + 1]) * U.p.wn[h];
      U.p.wv[t] = acc;
    }
    __syncthreads();
    if (t < 64) {
      float acc = 0.f;
      for (int m = 0; m < 64; ++m) {
        float ce = 0.f;
        for (int k = 0; k < 8; ++k) ce += convW[k * 4096 + t * 64 + m];
        acc += 0.125f * ce * U.p.wv[m];
      }
      ws[t] = acc;
    }
    if (t == 0) {
      float bh = 0.f;
      for (int h = 0; h < 256; ++h) bh += 0.5f * (bm[2 * h] + bm[2 * h + 1]) * U.p.wn[h];
      float bc = 0.f;
      for (int m = 0; m < 64; ++m) bc += convB[m] * U.p.wv[m];
      ws[64] = bh + bc + bo[0];
    }
    if (t < 64) {
      float a = 0.f;
      for (int k = 0; k < 64; ++k) a += b1[k] * U.p.sW2[k][t];
      ws[66 + t] = a;
    }
    {
      const int i = t >> 2, j0 = (t & 3) * 16;
      float acc[16];
#pragma unroll
      for (int jj = 0; jj < 16; ++jj) acc[jj] = 0.f;
      for (int k = 0; k < 64; ++k) {
        const float w1v = U.p.sW1[k][i];
#pragma unroll
        for (int jj = 0; jj < 16; ++jj) acc[jj] += w1v * U.p.sW2[k][j0 + jj];
      }
      _Float16* wsM = reinterpret_cast<_Float16*>(ws + 132);
#pragma unroll
      for (int jj = 0; jj < 16; ++jj) {
        const float x = acc[jj];
        const _Float16 h = (_Float16)x;
        wsM[i * 64 + j0 + jj] = h;
        wsM[4096 + i * 64 + j0 + jj] = (_Float16)(x - (float)h);
      }
    }
  }
}

// swizzled byte offset within a 36x64-half row-major tile (row stride 128 B)
__device__ __forceinline__ int swz(int row, int nbyte) {
  return row * 128 + (nbyte ^ ((row & 7) << 4));
}

// ---------------- per-(caption, image): hoisted B-frags + full chunk-ahead prefetch ----
__global__ __launch_bounds__(256, 4) void i2t_sim6(
    const float* __restrict__ images,
    const _Float16* __restrict__ capTH, const _Float16* __restrict__ capTL,
    const float* __restrict__ L, const float* __restrict__ dqT,
    const float* __restrict__ delt, const float* __restrict__ ws,
    float* __restrict__ out) {
  __shared__ union {
    float La[32][41];          // 5248 B (phases 1-3)
    _Float16 yhl[2][2304];     // 9216 B (tail)
  } UA;
  __shared__ union {
    _Float16 attn[2][36][40];  // 5760 B (live through chunk loop)
    float G[36][49];           // 7056 B (tail; cols 0..47 written by 3x16 tiles)
  } UB;
  __shared__ _Float16 simS[2][2304];  // 9216 B (swizzled rows)
  __shared__ float wrcp[32];
  __shared__ float sDelt[64], sCv[64], sU[64];
  __shared__ float sP[36], sScv[36], sRed[36];
  __shared__ float sBconst;

  const int t = threadIdx.x;
  const int lane = t & 63, wid = t >> 6;    // wid 0..3
  const int c = lane & 15, g = lane >> 4;
  const int bid = blockIdx.x;
  const int xcd = bid & 7, l = bid >> 3;    // l < 288
  const int ci = (xcd >> 1) * 12 + (l % 12);
  const int ii = (xcd & 1) * 24 + (l / 12);

  if (t < 64) { sDelt[t] = delt[t]; sCv[t] = ws[t]; sU[t] = ws[66 + t]; }
  if (t == 64) sBconst = ws[64];

  // ---- load L tile (already leaky'd)
#pragma unroll
  for (int k = 0; k < 2; ++k) {
    const int u = t + k * 256;
    if (u < 288) {
      const int w = u / 9, q4 = (u % 9) * 4;
      f32x4 x = *reinterpret_cast<const f32x4*>(
          L + (size_t)(ci * 32 + w) * 1728 + (size_t)ii * 36 + q4);
      *reinterpret_cast<f32x4*>(&UA.La[w][q4]) = x;
    }
  }
  __syncthreads();
  if (t < 32) {  // 1/l2norm over regions per word
    float s = 0.f;
    for (int ss = 0; ss < 36; ++ss) { const float v = UA.La[t][ss]; s += v * v; }
    wrcp[t] = 1.f / (sqrtf(s) + EPSF);
  }
  __syncthreads();
  if (t < 36) {  // softmax over words per region -> attn f16 hi/lo
    float lw[32];
    float m = -1e30f;
#pragma unroll
    for (int w = 0; w < 32; ++w) {
      const float v = 9.f * UA.La[w][t] * wrcp[w];
      lw[w] = v;
      m = fmaxf(m, v);
    }
    float sum = 0.f;
#pragma unroll
    for (int w = 0; w < 32; ++w) { lw[w] = expf(lw[w] - m); sum += lw[w]; }
    const float r = 1.f / sum;
#pragma unroll
    for (int w = 0; w < 32; ++w) {
      const float a = lw[w] * r;
      const _Float16 h = (_Float16)a;
      UB.attn[0][t][w] = h;
      UB.attn[1][t][w] = (_Float16)(a - (float)h);
    }
  }
  __syncthreads();

  // ---- chunk loop setup
  const size_t abase = ((size_t)ci * 1024 + wid * 16 + c) * 32 + g * 8;
  const float* pq[3];
  int scl[3];
  const float* pdqB = dqT + (size_t)ii * 64 * 36;
#pragma unroll
  for (int mt = 0; mt < 3; ++mt) {
    int s = mt * 16 + c; if (s > 35) s = 35;
    scl[mt] = s;
    pq[mt] = images + ((size_t)ii * 36 + s) * 1024 + wid * 16 + 4 * g;
  }
  // hoist chunk-invariant attn B-fragments into registers
  half8 Bh[3], Bl[3];
#pragma unroll
  for (int mt = 0; mt < 3; ++mt) {
    Bh[mt] = *reinterpret_cast<const half8*>(&UB.attn[0][scl[mt]][g * 8]);
    Bl[mt] = *reinterpret_cast<const half8*>(&UB.attn[1][scl[mt]][g * 8]);
  }
  // prefetch chunk 0 (capT + q + dq)
  half8 nAh = *reinterpret_cast<const half8*>(capTH + abase);
  half8 nAl = *reinterpret_cast<const half8*>(capTL + abase);
  f32x4 nqv[3];
  float ndq[3];
#pragma unroll
  for (int mt = 0; mt < 3; ++mt) {
    nqv[mt] = *reinterpret_cast<const f32x4*>(pq[mt]);
    ndq[mt] = pdqB[(size_t)wid * 36 + scl[mt]];
  }
#pragma unroll 1
  for (int ch = 0; ch < 16; ++ch) {
    const half8 Ah = nAh, Al = nAl;
    f32x4 qv[3];
    float dqv[3];
#pragma unroll
    for (int mt = 0; mt < 3; ++mt) { qv[mt] = nqv[mt]; dqv[mt] = ndq[mt]; }
    if (ch < 15) {  // issue next chunk's loads (full chunk of cover)
      const size_t nx = abase + (size_t)(ch + 1) * 64 * 32;
      nAh = *reinterpret_cast<const half8*>(capTH + nx);
      nAl = *reinterpret_cast<const half8*>(capTL + nx);
      const int nb1 = (ch + 1) * 4 + wid;
#pragma unroll
      for (int mt = 0; mt < 3; ++mt) {
        nqv[mt] = *reinterpret_cast<const f32x4*>(pq[mt] + (ch + 1) * 64);
        ndq[mt] = pdqB[(size_t)nb1 * 36 + scl[mt]];
      }
    }
    const int nb = ch * 4 + wid;
    // 3 independent MFMA+dot chains (all operands in registers)
    float dts[3], dcs[3];
#pragma unroll
    for (int mt = 0; mt < 3; ++mt) {
      f32x4 a = {0.f, 0.f, 0.f, 0.f};
      a = mfma16(Ah, Bh[mt], a);
      a = mfma16(Ah, Bl[mt], a);
      a = mfma16(Al, Bh[mt], a);
      const f32x4 q = qv[mt];
      dts[mt] = a[0] * q[0] + a[1] * q[1] + a[2] * q[2] + a[3] * q[3];
      dcs[mt] = a[0] * a[0] + a[1] * a[1] + a[2] * a[2] + a[3] * a[3];
    }
    // batched shuffle reductions + stores
#pragma unroll
    for (int mt = 0; mt < 3; ++mt) {
      float dt = dts[mt], dc = dcs[mt];
      dt += __shfl_xor(dt, 16); dc += __shfl_xor(dc, 16);
      dt += __shfl_xor(dt, 32); dc += __shfl_xor(dc, 32);
      const int s = mt * 16 + c;
      if (g == 0 && s < S) {
        const float r = __frsqrt_rn(fmaxf(dqv[mt] * dc, 1e-16f));
        const float sm = dt * r * sDelt[nb];
        const _Float16 h = (_Float16)sm;
        char* sb0 = (char*)&simS[0][0];
        char* sb1 = (char*)&simS[1][0];
        *reinterpret_cast<_Float16*>(sb0 + swz(s, nb * 2)) = h;
        *reinterpret_cast<_Float16*>(sb1 + swz(s, nb * 2)) = (_Float16)(sm - (float)h);
      }
    }
  }
  __syncthreads();

  // ---- tail
  const _Float16* wsM = reinterpret_cast<const _Float16*>(ws + 132);
  const char* sb0 = (const char*)&simS[0][0];
  const char* sb1 = (const char*)&simS[1][0];
  char* yb0 = (char*)&UA.yhl[0][0];
  char* yb1 = (char*)&UA.yhl[1][0];
  for (int tid = wid; tid < 12; tid += 4) {  // y = sim·M^T
    const int mt = tid >> 2, nt = tid & 3;
    f32x4 a = {0.f, 0.f, 0.f, 0.f};
#pragma unroll
    for (int ks = 0; ks < 2; ++ks) {
      const int ko = ks * 32 + g * 8;
      int ar = mt * 16 + c; if (ar > 35) ar = 35;
      half8 a_h = *reinterpret_cast<const half8*>(sb0 + swz(ar, ko * 2));
      half8 a_l = *reinterpret_cast<const half8*>(sb1 + swz(ar, ko * 2));
      half8 b_h = *reinterpret_cast<const half8*>(wsM + (nt * 16 + c) * 64 + ko);
      half8 b_l = *reinterpret_cast<const half8*>(wsM + 4096 + (nt * 16 + c) * 64 + ko);
      a = mfma16(a_h, b_h, a);
      a = mfma16(a_h, b_l, a);
      a = mfma16(a_l, b_h, a);
    }
#pragma unroll
    for (int r = 0; r < 4; ++r) {
      const int srow = mt * 16 + 4 * g + r;
      const int icol = nt * 16 + c;
      if (srow < S) {
        const float x = a[r];
        const _Float16 h = (_Float16)x;
        *reinterpret_cast<_Float16*>(yb0 + swz(srow, icol * 2)) = h;
        *reinterpret_cast<_Float16*>(yb1 + swz(srow, icol * 2)) = (_Float16)(x - (float)h);
      }
    }
  }
  if (t < 36) {  // p = u·sim ; scv = cv·sim (reads only simS)
    float a = 0.f, b = 0.f;
#pragma unroll
    for (int k8 = 0; k8 < 8; ++k8) {
      half8 v0 = *reinterpret_cast<const half8*>(sb0 + swz(t, k8 * 16));
      half8 v1 = *reinterpret_cast<const half8*>(sb1 + swz(t, k8 * 16));
#pragma unroll
      for (int j = 0; j < 8; ++j) {
        const float sv = (float)v0[j] + (float)v1[j];
        a += sv * sU[k8 * 8 + j];
        b += sv * sCv[k8 * 8 + j];
      }
    }
    sP[t] = a;
    sScv[t] = b;
  }
  __syncthreads();
  for (int tid = wid; tid < 9; tid += 4) {  // G = sim·y^T (UB.G; attn dead)
    const int mt = tid / 3, nt = tid % 3;
    f32x4 a = {0.f, 0.f, 0.f, 0.f};
#pragma unroll
    for (int ks = 0; ks < 2; ++ks) {
      const int ko = ks * 32 + g * 8;
      int ar = mt * 16 + c; if (ar > 35) ar = 35;
      int br = nt * 16 + c; if (br > 35) br = 35;
      half8 a_h = *reinterpret_cast<const half8*>(sb0 + swz(ar, ko * 2));
      half8 a_l = *reinterpret_cast<const half8*>(sb1 + swz(ar, ko * 2));
      half8 b_h = *reinterpret_cast<const half8*>((const char*)yb0 + swz(br, ko * 2));
      half8 b_l = *reinterpret_cast<const half8*>((const char*)yb1 + swz(br, ko * 2));
      a = mfma16(a_h, b_h, a);
      a = mfma16(a_h, b_l, a);
      a = mfma16(a_l, b_h, a);
    }
#pragma unroll
    for (int r = 0; r < 4; ++r) {
      const int srow = mt * 16 + 4 * g + r;
      const int tcol = nt * 16 + c;
      if (srow < S) UB.G[srow][tcol] = a[r];
    }
  }
  __syncthreads();
  if (t < 36) {  // fused row-softmax(G + p) · scv -> tanh
    float lg[36];
    float m = -1e30f;
#pragma unroll
    for (int t2 = 0; t2 < S; ++t2) {
      lg[t2] = UB.G[t][t2] + sP[t2];
      m = fmaxf(m, lg[t2]);
    }
    float se = 0.f, sv = 0.f;
#pragma unroll
    for (int t2 = 0; t2 < S; ++t2) {
      const float e = expf(lg[t2] - m);
      se += e; sv += e * sScv[t2];
    }
    sRed[t] = tanhf(sv / se + sBconst);
  }
  __syncthreads();
  if (t == 0) {
    float a = 0.f;
    for (int s = 0; s < S; ++s) a += sRed[s];
    out[(size_t)ii * NC + ci] = a * (1.f / 36.f);
  }
}

// ---------------- fallback (R2 kernel, used when ws too small) ----------------
constexpr int ST1 = CH + 8;
constexpr int STT = 56;
constexpr int STI = 68;
constexpr int STC = 52;
constexpr int STH = 72;
constexpr int STA = 40;

__global__ __launch_bounds__(256, 2) void i2t_fb(
    const float* __restrict__ images, const float* __restrict__ captions,
    const float* __restrict__ delt, const float* __restrict__ ws,
    float* __restrict__ out) {
  __shared__ union {
    struct { _Float16 cap[2][32][ST1]; _Float16 img[2][48][ST1]; } s1;
    float lpart[4][32][36];
    struct { _Float16 capT[2][64][STT]; float img32[36][STI]; } s2;
    _Float16 M[2][64][STH];
    float G[36][52];
  } rA;
  __shared__ union {
    float La[32][37];
    float ctxT[64][STC];
    _Float16 yhl[2][48][STH];
  } rB;
  __shared__ _Float16 attn_hl[2][48][STA];
  __shared__ _Float16 sim_hl[2][48][STH];
  __shared__ float wrcp[32];
  __shared__ float sDelt[64], sCv[64], sU[64];
  __shared__ float sP[36], sScv[36], sRed[36];
  __shared__ float sBconst;

  const int t = threadIdx.x;
  const int lane = t & 63, wid = t >> 6;
  const int mrow = lane & 15, grp = lane >> 4;
  const int bid = blockIdx.x;
  const int xcd = bid & 7, l = bid >> 3;
  const int ci = (xcd >> 1) * 12 + (l % 12);
  const int ii = (xcd & 1) * 24 + (l / 12);
  const float* cap = captions + ci * (W * D);
  const float* img = images + ii * (S * D);
  const f32x4 zero4 = {0.f, 0.f, 0.f, 0.f};

  if (t < 64) { sDelt[t] = delt[t]; sCv[t] = ws[t]; sU[t] = ws[66 + t]; }
  if (t == 64) sBconst = ws[64];

  f32x4 acc1[2][3];
#pragma unroll
  for (int mt = 0; mt < 2; ++mt)
#pragma unroll
    for (int nt = 0; nt < 3; ++nt) acc1[mt][nt] = zero4;

  for (int ch = 0; ch < NCH; ++ch) {
    const int d0 = ch * CH;
    __syncthreads();
    for (int q = t; q < 1088; q += 256) {
      const int row = q >> 4, c4 = (q & 15) * 4;
      const float* src = (row < 32) ? (cap + row * D + d0 + c4)
                                    : (img + (row - 32) * D + d0 + c4);
      float4 v = *reinterpret_cast<const float4*>(src);
      half4 hh, ll;
      hh[0] = (_Float16)v.x; ll[0] = (_Float16)(v.x - (float)hh[0]);
      hh[1] = (_Float16)v.y; ll[1] = (_Float16)(v.y - (float)hh[1]);
      hh[2] = (_Float16)v.z; ll[2] = (_Float16)(v.z - (float)hh[2]);
      hh[3] = (_Float16)v.w; ll[3] = (_Float16)(v.w - (float)hh[3]);
      _Float16* dh = (row < 32) ? &rA.s1.cap[0][row][c4] : &rA.s1.img[0][row - 32][c4];
      _Float16* dl = (row < 32) ? &rA.s1.cap[1][row][c4] : &rA.s1.img[1][row - 32][c4];
      *reinterpret_cast<half4*>(dh) = hh;
      *reinterpret_cast<half4*>(dl) = ll;
    }
    __syncthreads();
    if ((ch & 3) == wid) {
#pragma unroll
      for (int ks = 0; ks < 2; ++ks) {
        const int ko = ks * 32 + grp * 8;
        half8 ah[2], al[2], bh[3], bl[3];
#pragma unroll
        for (int mt = 0; mt < 2; ++mt) {
          ah[mt] = *reinterpret_cast<const half8*>(&rA.s1.cap[0][mt * 16 + mrow][ko]);
          al[mt] = *reinterpret_cast<const half8*>(&rA.s1.cap[1][mt * 16 + mrow][ko]);
        }
#pragma unroll
        for (int nt = 0; nt < 3; ++nt) {
          bh[nt] = *reinterpret_cast<const half8*>(&rA.s1.img[0][nt * 16 + mrow][ko]);
          bl[nt] = *reinterpret_cast<const half8*>(&rA.s1.img[1][nt * 16 + mrow][ko]);
        }
#pragma unroll
        for (int mt = 0; mt < 2; ++mt)
#pragma unroll
          for (int nt = 0; nt < 3; ++nt) {
            acc1[mt][nt] = mfma16(ah[mt], bh[nt], acc1[mt][nt]);
            acc1[mt][nt] = mfma16(ah[mt], bl[nt], acc1[mt][nt]);
            acc1[mt][nt] = mfma16(al[mt], bh[nt], acc1[mt][nt]);
          }
      }
    }
  }
  __syncthreads();
#pragma unroll
  for (int mt = 0; mt < 2; ++mt)
#pragma unroll
    for (int nt = 0; nt < 3; ++nt)
#pragma unroll
      for (int r = 0; r < 4; ++r) {
        const int w = mt * 16 + grp * 4 + r;
        const int s = nt * 16 + mrow;
        if (s < S) rA.lpart[wid][w][s] = acc1[mt][nt][r];
      }
  __syncthreads();
  {
    const float* lp = &rA.lpart[0][0][0];
    for (int e = t; e < W * S; e += 256) {
      float x = lp[e] + lp[e + 1152] + lp[e + 2304] + lp[e + 3456];
      x = x > 0.f ? x : 0.1f * x;
      rB.La[e / S][e % S] = x;
    }
  }
  __syncthreads();
  if (t < W) {
    float sum = 0.f;
    for (int s = 0; s < 36; ++s) { float v = rB.La[t][s]; sum += v * v; }
    wrcp[t] = 1.f / (sqrtf(sum) + EPSF);
  }
  __syncthreads();
  if (t < S) {
    float lw[32];
    float m = -1e30f;
#pragma unroll
    for (int w = 0; w < 32; ++w) {
      float v = 9.f * rB.La[w][t] * wrcp[w];
      lw[w] = v;
      m = fmaxf(m, v);
    }
    float sum = 0.f;
#pragma unroll
    for (int w = 0; w < 32; ++w) { lw[w] = expf(lw[w] - m); sum += lw[w]; }
    const float r = 1.f / sum;
#pragma unroll
    for (int w = 0; w < 32; ++w) {
      float a = lw[w] * r;
      _Float16 h = (_Float16)a;
      attn_hl[0][t][w] = h;
      attn_hl[1][t][w] = (_Float16)(a - (float)h);
    }
  }
  __syncthreads();

  half8 a2h[3], a2l[3];
#pragma unroll
  for (int mt = 0; mt < 3; ++mt) {
    a2h[mt] = *reinterpret_cast<const half8*>(&attn_hl[0][mt * 16 + mrow][grp * 8]);
    a2l[mt] = *reinterpret_cast<const half8*>(&attn_hl[1][mt * 16 + mrow][grp * 8]);
  }
  for (int ch = 0; ch < NCH; ++ch) {
    const int d0 = ch * CH;
    __syncthreads();
    {
      const int dl = t & 63, wb = (t >> 6) * 8;
      half8 hh, ll;
#pragma unroll
      for (int k = 0; k < 8; ++k) {
        float x = cap[(wb + k) * D + d0 + dl];
        hh[k] = (_Float16)x;
        ll[k] = (_Float16)(x - (float)hh[k]);
      }
      *reinterpret_cast<half8*>(&rA.s2.capT[0][dl][wb]) = hh;
      *reinterpret_cast<half8*>(&rA.s2.capT[1][dl][wb]) = ll;
    }
    for (int q = t; q < 576; q += 256) {
      const int sr = q >> 4, c4 = (q & 15) * 4;
      float4 v = *reinterpret_cast<const float4*>(img + sr * D + d0 + c4);
      *reinterpret_cast<float4*>(&rA.s2.img32[sr][c4]) = v;
    }
    __syncthreads();
    {
      const int dloc = wid * 16 + mrow;
      half8 b_h = *reinterpret_cast<const half8*>(&rA.s2.capT[0][dloc][grp * 8]);
      half8 b_l = *reinterpret_cast<const half8*>(&rA.s2.capT[1][dloc][grp * 8]);
#pragma unroll
      for (int mt = 0; mt < 3; ++mt) {
        f32x4 acc = zero4;
        acc = mfma16(a2h[mt], b_h, acc);
        acc = mfma16(a2h[mt], b_l, acc);
        acc = mfma16(a2l[mt], b_h, acc);
        const int s0 = mt * 16 + grp * 4;
        if (s0 < S) *reinterpret_cast<f32x4*>(&rB.ctxT[dloc][s0]) = acc;
      }
    }
    __syncthreads();
    if (t < 144) {
      const int s = t % 36, nbl = t / 36;
      const int n = ch * 4 + nbl;
      float dt = 0.f, dc = 0.f, dq = 0.f;
#pragma unroll
      for (int j4 = 0; j4 < 4; ++j4) {
        f32x4 qv = *reinterpret_cast<const f32x4*>(&rA.s2.img32[s][nbl * 16 + j4 * 4]);
#pragma unroll
        for (int jj = 0; jj < 4; ++jj) {
          float cx = rB.ctxT[nbl * 16 + j4 * 4 + jj][s];
          float q = qv[jj];
          dt += q * cx; dc += cx * cx; dq += q * q;
        }
      }
      float sim = dt / fmaxf(sqrtf(dq) * sqrtf(dc), EPSF) * sDelt[n];
      _Float16 h = (_Float16)sim;
      sim_hl[0][s][n] = h;
      sim_hl[1][s][n] = (_Float16)(sim - (float)h);
    }
  }
  __syncthreads();

  for (int q = t; q < 1024; q += 256) {
    const int hl = q >> 9, row = (q >> 3) & 63, c8 = (q & 7) * 8;
    const _Float16* wsM = reinterpret_cast<const _Float16*>(ws + 132);
    *reinterpret_cast<half8*>(&rA.M[hl][row][c8]) =
        *reinterpret_cast<const half8*>(wsM + hl * 4096 + row * 64 + c8);
  }
  __syncthreads();
  for (int tid = wid; tid < 12; tid += 4) {
    const int mt = tid >> 2, nt = tid & 3;
    f32x4 acc = zero4;
#pragma unroll
    for (int ks = 0; ks < 2; ++ks) {
      const int ko = ks * 32 + grp * 8;
      half8 a_h = *reinterpret_cast<const half8*>(&sim_hl[0][mt * 16 + mrow][ko]);
      half8 a_l = *reinterpret_cast<const half8*>(&sim_hl[1][mt * 16 + mrow][ko]);
      half8 b_h = *reinterpret_cast<const half8*>(&rA.M[0][nt * 16 + mrow][ko]);
      half8 b_l = *reinterpret_cast<const half8*>(&rA.M[1][nt * 16 + mrow][ko]);
      acc = mfma16(a_h, b_h, acc);
      acc = mfma16(a_h, b_l, acc);
      acc = mfma16(a_l, b_h, acc);
    }
#pragma unroll
    for (int r = 0; r < 4; ++r) {
      const int srow = mt * 16 + grp * 4 + r;
      const int icol = nt * 16 + mrow;
      float x = acc[r];
      _Float16 h = (_Float16)x;
      rB.yhl[0][srow][icol] = h;
      rB.yhl[1][srow][icol] = (_Float16)(x - (float)h);
    }
  }
  __syncthreads();
  for (int tid = wid; tid < 9; tid += 4) {
    const int mt = tid / 3, nt = tid % 3;
    f32x4 acc = zero4;
#pragma unroll
    for (int ks = 0; ks < 2; ++ks) {
      const int ko = ks * 32 + grp * 8;
      half8 a_h = *reinterpret_cast<const half8*>(&sim_hl[0][mt * 16 + mrow][ko]);
      half8 a_l = *reinterpret_cast<const half8*>(&sim_hl[1][mt * 16 + mrow][ko]);
      half8 b_h = *reinterpret_cast<const half8*>(&rB.yhl[0][nt * 16 + mrow][ko]);
      half8 b_l = *reinterpret_cast<const half8*>(&rB.yhl[1][nt * 16 + mrow][ko]);
      acc = mfma16(a_h, b_h, acc);
      acc = mfma16(a_h, b_l, acc);
      acc = mfma16(a_l, b_h, acc);
    }
#pragma unroll
    for (int r = 0; r < 4; ++r) {
      const int srow = mt * 16 + grp * 4 + r;
      const int tcol = nt * 16 + mrow;
      if (srow < S) rA.G[srow][tcol] = acc[r];
    }
  }
  __syncthreads();
  if (t < S) {
    float a = 0.f;
#pragma unroll
    for (int n = 0; n < 64; ++n)
      a += ((float)sim_hl[0][t][n] + (float)sim_hl[1][t][n]) * sU[n];
    sP[t] = a;
  } else if (t >= 64 && t < 64 + S) {
    const int r = t - 64;
    float a = 0.f;
#pragma unroll
    for (int n = 0; n < 64; ++n)
      a += ((float)sim_hl[0][r][n] + (float)sim_hl[1][r][n]) * sCv[n];
    sScv[r] = a;
  }
  __syncthreads();
  if (t < S) {
    float lg[36];
    float m = -1e30f;
#pragma unroll
    for (int t2 = 0; t2 < S; ++t2) {
      lg[t2] = rA.G[t][t2] + sP[t2];
      m = fmaxf(m, lg[t2]);
    }
    float se = 0.f, sv = 0.f;
#pragma unroll
    for (int t2 = 0; t2 < S; ++t2) {
      float e = expf(lg[t2] - m);
      se += e; sv += e * sScv[t2];
    }
    sRed[t] = tanhf(sv / se + sBconst);
  }
  __syncthreads();
  if (t == 0) {
    float a = 0.f;
    for (int s = 0; s < S; ++s) a += sRed[s];
    out[ii * NC + ci] = a * (1.f / 36.f);
  }
}

extern "C" void kernel_launch(void* const* d_in, const int* in_sizes, int n_in,
                              void* d_out, int out_size, void* d_ws, size_t ws_size,
                              hipStream_t stream) {
  const float* images   = (const float*)d_in[0];
  const float* captions = (const float*)d_in[1];
  // d_in[2] = cap_lens (unused: reference uniformizes to full length)
  const float* delt  = (const float*)d_in[3];
  const float* W1    = (const float*)d_in[4];
  const float* b1    = (const float*)d_in[5];
  const float* W2    = (const float*)d_in[6];
  // d_in[7] = b2: cancels inside the row-softmax, unused
  const float* convW = (const float*)d_in[8];
  const float* convB = (const float*)d_in[9];
  const float* Wm    = (const float*)d_in[10];
  const float* bm    = (const float*)d_in[11];
  const float* V     = (const float*)d_in[12];
  const float* g     = (const float*)d_in[13];
  const float* bo    = (const float*)d_in[14];
  float* ws  = (float*)d_ws;
  float* out = (float*)d_out;

  if (ws_size >= WS_NEED) {
    char* base = (char*)d_ws;
    _Float16* capTH = (_Float16*)(base + OFF_CAPTH);
    _Float16* capTL = (_Float16*)(base + OFF_CAPTL);
    float*    Lbuf  = (float*)(base + OFF_L);
    float*    dqT   = (float*)(base + OFF_DQ);
    fused_pre<<<dim3(1249), 256, 0, stream>>>(captions, images, W1, b1, W2,
                                              convW, convB, Wm, bm, V, g, bo,
                                              ws, capTH, capTL, dqT, Lbuf);
    i2t_sim6<<<dim3(2304), 256, 0, stream>>>(images, capTH, capTL, Lbuf, dqT,
                                             delt, ws, out);
  } else {
    prep_kernel<<<1, 256, 0, stream>>>(W1, b1, W2, convW, convB, Wm, bm, V, g, bo, ws);
    i2t_fb<<<dim3(NI * NC), 256, 0, stream>>>(images, captions, delt, ws, out);
  }
}